// Round 3
// baseline (42756.320 us; speedup 1.0000x reference)
//
#include <hip/hip_runtime.h>

typedef float  f32x4  __attribute__((ext_vector_type(4)));
typedef short  bf16x8 __attribute__((ext_vector_type(8)));
typedef unsigned int u32x4 __attribute__((ext_vector_type(4)));

#define DEVI static __device__ __forceinline__

namespace {
constexpr int kL   = 512;
constexpr int kN   = 64;
constexpr int kDH  = 512;
constexpr int kDIN = 512;
constexpr int kG   = 2048;            // 4*kDH
constexpr int kT   = 32;              // timesteps per chunk
constexpr int kChunks = kL / kT;      // 16
constexpr size_t kOutSz = (size_t)kL * kN * kDIN;  // 16,777,216 floats
constexpr unsigned kSent   = 0x7FC0u;        // bf16 NaN sentinel (h in (-1,1) can't produce it)
constexpr unsigned kSent32 = 0x7FC07FC0u;
}

struct Claim { unsigned ticket, done, xmask, pad; };

DEVI unsigned short f2bf(float f) {
  union { float f; unsigned u; } v; v.f = f;
  unsigned r = v.u + 0x7FFFu + ((v.u >> 16) & 1u);   // RNE
  return (unsigned short)(r >> 16);
}
DEVI float bf2f(unsigned short b) {
  union { unsigned u; float f; } v; v.u = ((unsigned)b) << 16;
  return v.f;
}
DEVI float sigm(float z) { return 1.f / (1.f + __expf(-z)); }
DEVI float tanh_f(float z) { return 2.f / (1.f + __expf(-2.f * z)) - 1.f; }

// ---------------------------------------------------------------- prep
__global__ void prep_kernel(
    const float* __restrict__ Wf, const float* __restrict__ Wc,
    const float* __restrict__ Wi, const float* __restrict__ Wo,
    const float* __restrict__ bf, const float* __restrict__ bc,
    const float* __restrict__ bi, const float* __restrict__ bo,
    const float* __restrict__ Wout,
    const float* __restrict__ h0, const float* __restrict__ c0,
    unsigned short* __restrict__ WxT, unsigned short* __restrict__ WoT,
    unsigned short* __restrict__ WhB, float* __restrict__ bg,
    unsigned short* __restrict__ hsx, float* __restrict__ cbuf,
    unsigned* __restrict__ claims)
{
  const int gid = blockIdx.x * blockDim.x + threadIdx.x;
  const int stride = gridDim.x * blockDim.x;
  const float* Wg[4]  = {Wf, Wc, Wi, Wo};
  const float* bgs[4] = {bf, bc, bi, bo};

  // zero the 16 per-chunk claim sets (ticket/done/xmask/pad)
  for (int i = gid; i < 16 * 4; i += stride) claims[i] = 0u;

  for (int i = gid; i < kG * 512; i += stride) {
    int k = i >> 11, g = i & 2047;
    WxT[(size_t)g * 512 + k] = f2bf(Wg[g >> 9][(size_t)k * 512 + (g & 511)]);
  }
  for (int i = gid; i < 512 * 512; i += stride) {
    int k = i >> 9, c = i & 511;
    WoT[(size_t)c * 512 + k] = f2bf(Wout[(size_t)k * 512 + c]);
  }
  // WhB: i = k*1024 + gate*512 + hcol  -> coalesced source reads
  for (int i = gid; i < 4 * 512 * 512; i += stride) {
    int hcol = i & 511;
    int gate = (i >> 9) & 3;
    int k    = i >> 11;
    int cg = hcol >> 3, jj = hcol & 7;
    int n  = gate * 8 + jj;
    int kblk = k >> 3, kin = k & 7;
    size_t dst = ((size_t)cg * 32 + n) * 512 + (((kblk ^ (n & 7)) << 3) | kin);
    WhB[dst] = f2bf(Wg[gate][(size_t)(512 + k) * 512 + hcol]);
  }
  for (int i = gid; i < kG; i += stride) bg[i] = bgs[i >> 9][i & 511];
  for (int i = gid; i < kN * kDH; i += stride) {
    hsx[i]  = f2bf(h0[i]);   // hsx[0] = h0
    cbuf[i] = c0[i];
  }
  // sentinel-fill hsx[1..512]: consumers poll the data itself (no flags).
  {
    unsigned* h32 = (unsigned*)hsx;
    const int base = (kN * kDH) / 2;                 // u32 offset of step 1
    const int cnt  = (kL * kN * kDH) / 2;            // 8,388,608 u32
    for (int i = gid; i < cnt; i += stride) h32[base + i] = kSent32;
  }
}

// Shared-memory for the gemm kernels.
struct SMem {
  struct { unsigned short Ash[128][40]; unsigned short Bsh[128][40]; } g;  // 20 KB
};

// ---------------------------------------------------------------- gemm_x body
// Zx2[cg][row][n] = x_row . Wx[:,col] + bg[col]; col = gate*512+cg*8+jj, n = gate*8+jj.
DEVI void gemm_x_tile(SMem& sm, const float* __restrict__ X,
                      const unsigned short* __restrict__ WxT,
                      const float* __restrict__ bg,
                      float* __restrict__ Zx2, int row0, int col0, int tid)
{
  const int lane = tid & 63, wave = tid >> 6;
  const int wr = wave >> 1, wc = wave & 1;
  const int m16 = lane & 15, kg = (lane >> 4) * 8;

  f32x4 acc[4][4] = {};

  for (int k0 = 0; k0 < 512; k0 += 32) {
    __syncthreads();
    #pragma unroll
    for (int i = 0; i < 4; ++i) {
      int idx = i * 256 + tid;
      int r = idx >> 3, kq = idx & 7;
      float4 v = *(const float4*)&X[(size_t)(row0 + r) * 512 + k0 + kq * 4];
      unsigned short* dst = &sm.g.Ash[r][kq * 4];
      dst[0] = f2bf(v.x); dst[1] = f2bf(v.y); dst[2] = f2bf(v.z); dst[3] = f2bf(v.w);
    }
    #pragma unroll
    for (int i = 0; i < 2; ++i) {
      int idx = i * 256 + tid;
      int c = idx >> 2, kq = idx & 3;
      *(uint4*)&sm.g.Bsh[c][kq * 8] =
          *(const uint4*)&WxT[(size_t)(col0 + c) * 512 + k0 + kq * 8];
    }
    __syncthreads();
    bf16x8 fa[4], fb[4];
    #pragma unroll
    for (int mi = 0; mi < 4; ++mi) fa[mi] = *(const bf16x8*)&sm.g.Ash[wr*64 + mi*16 + m16][kg];
    #pragma unroll
    for (int ni = 0; ni < 4; ++ni) fb[ni] = *(const bf16x8*)&sm.g.Bsh[wc*64 + ni*16 + m16][kg];
    #pragma unroll
    for (int mi = 0; mi < 4; ++mi)
      #pragma unroll
      for (int ni = 0; ni < 4; ++ni)
        acc[mi][ni] = __builtin_amdgcn_mfma_f32_16x16x32_bf16(fa[mi], fb[ni], acc[mi][ni], 0, 0, 0);
  }
  const int rg = (lane >> 4) * 4;
  #pragma unroll
  for (int ni = 0; ni < 4; ++ni) {
    int col = col0 + wc*64 + ni*16 + m16;
    float bb = bg[col];
    int gate = col >> 9, hcol = col & 511;
    int cg = hcol >> 3, n = gate * 8 + (hcol & 7);
    #pragma unroll
    for (int mi = 0; mi < 4; ++mi)
      #pragma unroll
      for (int r = 0; r < 4; ++r) {
        int row = row0 + wr*64 + mi*16 + rg + r;
        Zx2[((size_t)cg * 2048 + row) * 32 + n] = acc[mi][ni][r] + bb;
      }
  }
}

// ---------------------------------------------------------------- gemm_x (full-GPU dispatch per chunk)
__global__ __launch_bounds__(256) void gemm_x_kernel(
    const float* __restrict__ X, const unsigned short* __restrict__ WxT,
    const float* __restrict__ bg, float* __restrict__ Zx2)
{
  __shared__ SMem sm;
  gemm_x_tile(sm, X, WxT, bg, Zx2, blockIdx.x * 128, blockIdx.y * 128, threadIdx.x);
}

// ---------------------------------------------------------------- rec loop body
// L2 == 1: all 64 worker blocks verified on one XCD -> h hand-off stays in
// that XCD's shared L2 (plain write-through stores; sc0 loads bypass L0 only).
// L2 == 0: cross-XCD fallback -> IC path (sc0 sc1), exactly round-2 behavior.
template<int L2MODE>
DEVI void rec_loop(const unsigned short* WT, int cg, int tid,
                   const float* __restrict__ Zxcur,
                   unsigned short* __restrict__ hsx,
                   float* __restrict__ cbuf,
                   int step0, float* __restrict__ dout)
{
  const int j0  = cg * 8;
  const int w   = tid >> 6;           // wave 0..3 -> batch rows w*16..+16
  const int l   = tid & 63;
  const int q   = l & 15;             // n-col within frag
  const int lg  = l >> 4;             // k-group
  const int jj  = q & 7;
  const int i0  = (q < 8) ? 0 : 2;    // acc rows this lane finishes

  const size_t cidx = (size_t)(w * 16 + lg * 4 + i0) * 512 + j0 + jj;
  float c0r = cbuf[cidx];
  float c1r = cbuf[cidx + 512];

  // Zx for t=0
  float zc0[4], zc1[4];
  {
    const float* zb = Zxcur + ((size_t)cg * 2048 + (w * 16 + lg * 4)) * 32 + q;
    #pragma unroll
    for (int i = 0; i < 4; ++i) { zc0[i] = zb[i * 32]; zc1[i] = zb[i * 32 + 16]; }
  }

  for (int t = 0; t < kT; ++t) {
    const int st = step0 + t;

    // -------- poll-load A frags (16 x 16B of row w*16+q) until no sentinel.
    const unsigned short* hrow =
        hsx + (size_t)st * (kN * kDH) + (w * 16 + q) * 512 + lg * 8;
    u32x4 av[16];
    int spin = 0;
    for (;;) {
      #pragma unroll
      for (int s = 0; s < 16; ++s) {
        if (L2MODE)
          asm volatile("global_load_dwordx4 %0, %1, off offset:%2 sc0"
                       : "=v"(av[s]) : "v"(hrow), "i"(64 * s));
        else
          asm volatile("global_load_dwordx4 %0, %1, off offset:%2 sc0 sc1"
                       : "=v"(av[s]) : "v"(hrow), "i"(64 * s));
      }
      asm volatile("s_waitcnt vmcnt(0)" ::: "memory");
      __builtin_amdgcn_sched_barrier(0);
      unsigned bad = 0;
      #pragma unroll
      for (int s = 0; s < 16; ++s) {
        bad |= ((av[s][0] & 0xFFFFu) == kSent);
        bad |= ((av[s][1] & 0xFFFFu) == kSent);
        bad |= ((av[s][2] & 0xFFFFu) == kSent);
        bad |= ((av[s][3] & 0xFFFFu) == kSent);
      }
      if (!__any(bad)) break;
      if (++spin > 1024) {
        // rescue: agent-scope atomic loads route through the local TCC (see
        // dirty L2 lines) and to IC for remote data — correctness net.
        const unsigned long long* hp = (const unsigned long long*)hrow;
        bad = 0;
        #pragma unroll
        for (int s = 0; s < 16; ++s) {
          union { unsigned long long q2[2]; u32x4 v4; } uu;
          uu.q2[0] = __hip_atomic_load(hp + 8 * s,     __ATOMIC_RELAXED,
                                       __HIP_MEMORY_SCOPE_AGENT);
          uu.q2[1] = __hip_atomic_load(hp + 8 * s + 1, __ATOMIC_RELAXED,
                                       __HIP_MEMORY_SCOPE_AGENT);
          av[s] = uu.v4;
          bad |= ((av[s][0] & 0xFFFFu) == kSent);
          bad |= ((av[s][1] & 0xFFFFu) == kSent);
          bad |= ((av[s][2] & 0xFFFFu) == kSent);
          bad |= ((av[s][3] & 0xFFFFu) == kSent);
        }
        if (!__any(bad)) break;
        spin = 1025;   // stay on rescue cadence
      }
    }

    // Zx prefetch for t+1: issued before MFMA, completes under compute.
    float zn0[4], zn1[4];
    if (t + 1 < kT) {
      const float* zb = Zxcur +
          ((size_t)cg * 2048 + ((t + 1) * 64 + w * 16 + lg * 4)) * 32 + q;
      #pragma unroll
      for (int i = 0; i < 4; ++i) { zn0[i] = zb[i * 32]; zn1[i] = zb[i * 32 + 16]; }
    }

    // MFMA: 16 ksteps x 2 n-frags
    f32x4 acc0 = {}, acc1 = {};
    #pragma unroll
    for (int s = 0; s < 16; ++s) {
      const int kb = 4 * s + lg;
      bf16x8 b0 = *(const bf16x8*)&WT[(size_t)q * 512 + ((kb ^ jj) << 3)];
      bf16x8 b1 = *(const bf16x8*)&WT[(size_t)(16 + q) * 512 + ((kb ^ jj) << 3)];
      union { u32x4 u; bf16x8 a; } ua; ua.u = av[s];
      acc0 = __builtin_amdgcn_mfma_f32_16x16x32_bf16(ua.a, b0, acc0, 0, 0, 0);
      acc1 = __builtin_amdgcn_mfma_f32_16x16x32_bf16(ua.a, b1, acc1, 0, 0, 0);
    }

    // z = acc + Zx (own cols), then exchange with lane^8 to gather 4 gates
    float t0[4], t1[4], ot0[4], ot1[4];
    #pragma unroll
    for (int i = 0; i < 4; ++i) { t0[i] = acc0[i] + zc0[i]; t1[i] = acc1[i] + zc1[i]; }
    #pragma unroll
    for (int i = 0; i < 4; ++i) {
      ot0[i] = __shfl_xor(t0[i], 8, 64);
      ot1[i] = __shfl_xor(t1[i], 8, 64);
    }
    float hh[2];
    #pragma unroll
    for (int u = 0; u < 2; ++u) {
      const int i = i0 + u;
      float zf = (q < 8) ? t0[i] : ot0[i];
      float zc = (q < 8) ? ot0[i] : t0[i];
      float zi = (q < 8) ? t1[i] : ot1[i];
      float zo = (q < 8) ? ot1[i] : t1[i];
      float fg = sigm(zf), ig = sigm(zi), og = sigm(zo);
      float Ct = tanh_f(zc);
      float& cr = u ? c1r : c0r;
      cr = fg * cr + ig * Ct;
      hh[u] = og * tanh_f(cr);
    }

    // store h (bf16 pairs packed into one dword => atomic halves).
    {
      unsigned short hb0 = f2bf(hh[0]), hb1 = f2bf(hh[1]);
      unsigned o0 = (unsigned)(unsigned short)__shfl_xor((int)hb0, 1, 64);
      unsigned o1 = (unsigned)(unsigned short)__shfl_xor((int)hb1, 1, 64);
      if ((q & 1) == 0) {
        const size_t base = (size_t)(st + 1) * (kN * kDH) +
                            (size_t)(w * 16 + lg * 4 + i0) * 512 + j0 + jj;
        unsigned v0 = ((unsigned)hb0) | (o0 << 16);
        unsigned v1 = ((unsigned)hb1) | (o1 << 16);
        if (L2MODE) {
          // write-through L0 -> local (shared) L2; consumers poll with sc0
          *(volatile unsigned*)&hsx[base]       = v0;
          *(volatile unsigned*)&hsx[base + 512] = v1;
        } else {
          __hip_atomic_store((unsigned*)&hsx[base], v0,
                             __ATOMIC_RELAXED, __HIP_MEMORY_SCOPE_AGENT);
          __hip_atomic_store((unsigned*)&hsx[base + 512], v1,
                             __ATOMIC_RELAXED, __HIP_MEMORY_SCOPE_AGENT);
        }
      }
      if (st == kL - 1) {
        dout[kOutSz + cidx] = hh[0];
        dout[kOutSz + cidx + 512] = hh[1];
        dout[kOutSz + (size_t)kN * kDH + cidx] = c0r;
        dout[kOutSz + (size_t)kN * kDH + cidx + 512] = c1r;
      }
    }

    if (t + 1 < kT) {
      #pragma unroll
      for (int i = 0; i < 4; ++i) { zc0[i] = zn0[i]; zc1[i] = zn1[i]; }
    }
  }

  cbuf[cidx] = c0r;
  cbuf[cidx + 512] = c1r;
}

// ---------------------------------------------------------------- rec kernel (XCD-claimed workers)
__global__ __launch_bounds__(256, 1) void lstm_rec_kernel(
    const unsigned short* __restrict__ WhB,  // [64][32][512] bf16 swizzled
    const float* __restrict__ Zxcur,         // [64][2048][32] this chunk
    unsigned short* __restrict__ hsx,        // [513][64][512] bf16 history
    float* __restrict__ cbuf,                // [64][512] fp32
    int step0,
    float* __restrict__ dout,
    Claim* __restrict__ cs)
{
  __shared__ unsigned short WT[32 * 512];    // 32 KB
  __shared__ int s_slot, s_mode;
  const int tid = threadIdx.x;

  // ---- claim phase: prefer XCD 0; timed fallback guarantees 64 workers ----
  if (tid == 0) {
    unsigned xcd;
    asm volatile("s_getreg_b32 %0, hwreg(HW_REG_XCC_ID)" : "=s"(xcd));
    xcd &= 7u;
    int slot = -1;
    if (xcd == 0u) {
      unsigned t = __hip_atomic_fetch_add(&cs->ticket, 1u, __ATOMIC_RELAXED,
                                          __HIP_MEMORY_SCOPE_AGENT);
      if (t < 64u) slot = (int)t;
    } else {
      unsigned long long t0 = __builtin_amdgcn_s_memrealtime();
      for (;;) {
        unsigned tk = __hip_atomic_load(&cs->ticket, __ATOMIC_RELAXED,
                                        __HIP_MEMORY_SCOPE_AGENT);
        if (tk >= 64u) break;                              // filled: not needed
        if (__builtin_amdgcn_s_memrealtime() - t0 > 2500ULL) {   // ~25 us
          unsigned t = __hip_atomic_fetch_add(&cs->ticket, 1u, __ATOMIC_RELAXED,
                                              __HIP_MEMORY_SCOPE_AGENT);
          if (t < 64u) slot = (int)t;
          break;
        }
        __builtin_amdgcn_s_sleep(32);
      }
    }
    int mode = 0;
    if (slot >= 0) {
      __hip_atomic_fetch_or(&cs->xmask, 1u << xcd, __ATOMIC_RELEASE,
                            __HIP_MEMORY_SCOPE_AGENT);
      __hip_atomic_fetch_add(&cs->done, 1u, __ATOMIC_ACQ_REL,
                             __HIP_MEMORY_SCOPE_AGENT);
      while (__hip_atomic_load(&cs->done, __ATOMIC_ACQUIRE,
                               __HIP_MEMORY_SCOPE_AGENT) < 64u)
        __builtin_amdgcn_s_sleep(16);
      unsigned xm = __hip_atomic_load(&cs->xmask, __ATOMIC_ACQUIRE,
                                      __HIP_MEMORY_SCOPE_AGENT);
      mode = (__popc(xm) == 1) ? 1 : 0;   // all workers on one XCD?
    }
    s_slot = slot; s_mode = mode;
  }
  __syncthreads();
  const int slot = s_slot, mode = s_mode;
  if (slot < 0) return;
  const int cg = slot;

  // one-time: W slice -> LDS (linear copy; swizzle pre-applied by prep)
  {
    const uint4* wsrc = (const uint4*)(WhB + (size_t)cg * 32 * 512);
    uint4* wdst = (uint4*)WT;
    #pragma unroll
    for (int i = 0; i < 8; ++i) wdst[i * 256 + tid] = wsrc[i * 256 + tid];
  }
  __syncthreads();

  if (mode) rec_loop<1>(WT, cg, tid, Zxcur, hsx, cbuf, step0, dout);
  else      rec_loop<0>(WT, cg, tid, Zxcur, hsx, cbuf, step0, dout);
}

// ---------------------------------------------------------------- gemm_out
__global__ __launch_bounds__(256) void gemm_out_kernel(
    const unsigned short* __restrict__ Hs,   // [32768][512] bf16 (h_1..h_512)
    const unsigned short* __restrict__ WoT,  // [512][512] bf16 (B^T)
    const float* __restrict__ bout,
    float* __restrict__ out)                 // [32768][512] fp32
{
  __shared__ unsigned short Ash[128][40];
  __shared__ unsigned short Bsh[128][40];
  const int row0 = blockIdx.x * 128, col0 = blockIdx.y * 128;
  const int tid = threadIdx.x;
  const int lane = tid & 63, wave = tid >> 6;
  const int wr = wave >> 1, wc = wave & 1;
  const int m16 = lane & 15, kg = (lane >> 4) * 8;

  f32x4 acc[4][4] = {};

  for (int k0 = 0; k0 < 512; k0 += 32) {
    __syncthreads();
    #pragma unroll
    for (int i = 0; i < 2; ++i) {
      int idx = i * 256 + tid;
      int r = idx >> 2, kq = idx & 3;
      *(uint4*)&Ash[r][kq * 8] =
          *(const uint4*)&Hs[(size_t)(row0 + r) * 512 + k0 + kq * 8];
    }
    #pragma unroll
    for (int i = 0; i < 2; ++i) {
      int idx = i * 256 + tid;
      int c = idx >> 2, kq = idx & 3;
      *(uint4*)&Bsh[c][kq * 8] =
          *(const uint4*)&WoT[(size_t)(col0 + c) * 512 + k0 + kq * 8];
    }
    __syncthreads();
    bf16x8 fa[4], fb[4];
    #pragma unroll
    for (int mi = 0; mi < 4; ++mi) fa[mi] = *(const bf16x8*)&Ash[wr*64 + mi*16 + m16][kg];
    #pragma unroll
    for (int ni = 0; ni < 4; ++ni) fb[ni] = *(const bf16x8*)&Bsh[wc*64 + ni*16 + m16][kg];
    #pragma unroll
    for (int mi = 0; mi < 4; ++mi)
      #pragma unroll
      for (int ni = 0; ni < 4; ++ni)
        acc[mi][ni] = __builtin_amdgcn_mfma_f32_16x16x32_bf16(fa[mi], fb[ni], acc[mi][ni], 0, 0, 0);
  }
  const int rg = (lane >> 4) * 4;
  #pragma unroll
  for (int ni = 0; ni < 4; ++ni) {
    int col = col0 + wc*64 + ni*16 + m16;
    float bb = bout[col];
    #pragma unroll
    for (int mi = 0; mi < 4; ++mi)
      #pragma unroll
      for (int r = 0; r < 4; ++r)
        out[(size_t)(row0 + wr*64 + mi*16 + rg + r) * 512 + col] = acc[mi][ni][r] + bb;
  }
}

// ---------------------------------------------------------------- launch
extern "C" void kernel_launch(void* const* d_in, const int* in_sizes, int n_in,
                              void* d_out, int out_size, void* d_ws, size_t ws_size,
                              hipStream_t stream) {
  (void)in_sizes; (void)n_in; (void)out_size; (void)ws_size;
  const float* x    = (const float*)d_in[0];
  const float* h0   = (const float*)d_in[1];
  const float* c0   = (const float*)d_in[2];
  const float* Wf   = (const float*)d_in[3];
  const float* bf_  = (const float*)d_in[4];
  const float* Wc   = (const float*)d_in[5];
  const float* bc_  = (const float*)d_in[6];
  const float* Wi_  = (const float*)d_in[7];
  const float* bi_  = (const float*)d_in[8];
  const float* Wo   = (const float*)d_in[9];
  const float* bo_  = (const float*)d_in[10];
  const float* Wout = (const float*)d_in[11];
  const float* bout = (const float*)d_in[12];
  float* out = (float*)d_out;

  char* ws = (char*)d_ws;
  size_t off = 0;
  auto alloc = [&](size_t bytes) -> void* {
    void* p = ws + off;
    off += (bytes + 255) & ~(size_t)255;
    return p;
  };
  float*          ZxA = (float*)alloc((size_t)kT * kN * kG * 4);                 // 16 MB
  float*          ZxB = (float*)alloc((size_t)kT * kN * kG * 4);                 // 16 MB
  unsigned short* hsx = (unsigned short*)alloc((size_t)(kL + 1) * kN * kDH * 2); // 33.6 MB
  unsigned short* WxT = (unsigned short*)alloc((size_t)kG * 512 * 2);            // 2 MB
  unsigned short* WoT = (unsigned short*)alloc((size_t)512 * 512 * 2);           // 0.5 MB
  unsigned short* WhB = (unsigned short*)alloc((size_t)64 * 32 * 512 * 2);       // 2 MB
  float*          bg  = (float*)alloc((size_t)kG * 4);
  float*          cbf = (float*)alloc((size_t)kN * kDH * 4);
  Claim*          cls = (Claim*)alloc(16 * sizeof(Claim));

  prep_kernel<<<1024, 256, 0, stream>>>(Wf, Wc, Wi_, Wo, bf_, bc_, bi_, bo_,
                                        Wout, h0, c0, WxT, WoT, WhB, bg, hsx, cbf,
                                        (unsigned*)cls);
  // chunk 0's Zx
  gemm_x_kernel<<<dim3(16, 16), 256, 0, stream>>>(x, WxT, bg, ZxA);
  for (int c = 0; c < kChunks; ++c) {
    float* Zxcur = (c & 1) ? ZxB : ZxA;
    float* Zxnxt = (c & 1) ? ZxA : ZxB;
    lstm_rec_kernel<<<512, 256, 0, stream>>>(
        WhB, Zxcur, hsx, cbf, c * kT, out, &cls[c]);
    if (c + 1 < kChunks) {
      const float* xnext = x + (size_t)(c + 1) * kT * kN * kDIN;
      gemm_x_kernel<<<dim3(16, 16), 256, 0, stream>>>(xnext, WxT, bg, Zxnxt);
    }
  }
  gemm_out_kernel<<<dim3(256, 4), 256, 0, stream>>>(
      hsx + (size_t)kN * kDH, WoT, bout, out);
}

// Round 4
// 5818.188 us; speedup vs baseline: 7.3487x; 7.3487x over previous
//
#include <hip/hip_runtime.h>

typedef float  f32x4  __attribute__((ext_vector_type(4)));
typedef short  bf16x8 __attribute__((ext_vector_type(8)));
typedef unsigned int u32x4 __attribute__((ext_vector_type(4)));

#define DEVI static __device__ __forceinline__

namespace {
constexpr int kL   = 512;
constexpr int kN   = 64;
constexpr int kDH  = 512;
constexpr int kDIN = 512;
constexpr int kG   = 2048;            // 4*kDH
constexpr int kT   = 32;              // timesteps per chunk
constexpr int kChunks = kL / kT;      // 16
constexpr size_t kOutSz = (size_t)kL * kN * kDIN;  // 16,777,216 floats
constexpr unsigned kSent   = 0x7FC0u;        // bf16 NaN sentinel (h in (-1,1) can't produce it)
constexpr unsigned kSent32 = 0x7FC07FC0u;
}

DEVI unsigned short f2bf(float f) {
  union { float f; unsigned u; } v; v.f = f;
  unsigned r = v.u + 0x7FFFu + ((v.u >> 16) & 1u);   // RNE
  return (unsigned short)(r >> 16);
}
DEVI float bf2f(unsigned short b) {
  union { unsigned u; float f; } v; v.u = ((unsigned)b) << 16;
  return v.f;
}
DEVI float sigm(float z) { return 1.f / (1.f + __expf(-z)); }
DEVI float tanh_f(float z) { return 2.f / (1.f + __expf(-2.f * z)) - 1.f; }

// ---------------------------------------------------------------- prep
__global__ void prep_kernel(
    const float* __restrict__ Wf, const float* __restrict__ Wc,
    const float* __restrict__ Wi, const float* __restrict__ Wo,
    const float* __restrict__ bf, const float* __restrict__ bc,
    const float* __restrict__ bi, const float* __restrict__ bo,
    const float* __restrict__ Wout,
    const float* __restrict__ h0, const float* __restrict__ c0,
    unsigned short* __restrict__ WxT, unsigned short* __restrict__ WoT,
    unsigned short* __restrict__ WhB, float* __restrict__ bg,
    unsigned short* __restrict__ hsx, float* __restrict__ cbuf,
    unsigned int* __restrict__ flags)
{
  const int gid = blockIdx.x * blockDim.x + threadIdx.x;
  const int stride = gridDim.x * blockDim.x;
  const float* Wg[4]  = {Wf, Wc, Wi, Wo};
  const float* bgs[4] = {bf, bc, bi, bo};

  for (int i = gid; i < 64; i += stride) flags[i] = 0u;   // wave-step counters

  for (int i = gid; i < kG * 512; i += stride) {
    int k = i >> 11, g = i & 2047;
    WxT[(size_t)g * 512 + k] = f2bf(Wg[g >> 9][(size_t)k * 512 + (g & 511)]);
  }
  for (int i = gid; i < 512 * 512; i += stride) {
    int k = i >> 9, c = i & 511;
    WoT[(size_t)c * 512 + k] = f2bf(Wout[(size_t)k * 512 + c]);
  }
  // WhB: i = k*1024 + gate*512 + hcol  -> coalesced source reads
  for (int i = gid; i < 4 * 512 * 512; i += stride) {
    int hcol = i & 511;
    int gate = (i >> 9) & 3;
    int k    = i >> 11;
    int cg = hcol >> 3, jj = hcol & 7;
    int n  = gate * 8 + jj;
    int kblk = k >> 3, kin = k & 7;
    size_t dst = ((size_t)cg * 32 + n) * 512 + (((kblk ^ (n & 7)) << 3) | kin);
    WhB[dst] = f2bf(Wg[gate][(size_t)(512 + k) * 512 + hcol]);
  }
  for (int i = gid; i < kG; i += stride) bg[i] = bgs[i >> 9][i & 511];
  for (int i = gid; i < kN * kDH; i += stride) {
    hsx[i]  = f2bf(h0[i]);   // hsx[0] = h0
    cbuf[i] = c0[i];
  }
  // sentinel-fill hsx[1..512]: consumers validate data arrival (net under
  // the unordered flag publish).
  {
    unsigned* h32 = (unsigned*)hsx;
    const int base = (kN * kDH) / 2;                 // u32 offset of step 1
    const int cnt  = (kL * kN * kDH) / 2;            // 8,388,608 u32
    for (int i = gid; i < cnt; i += stride) h32[base + i] = kSent32;
  }
}

// Shared-memory overlay for the fused kernel's two roles.
struct SMem {
  union {
    unsigned short WT[32 * 512];                                   // rec: 32 KB
    struct { unsigned short Ash[128][40]; unsigned short Bsh[128][40]; } g;  // 20 KB
  };
};

// ---------------------------------------------------------------- gemm_x body
// Zx2[cg][row][n] = x_row . Wx[:,col] + bg[col]; col = gate*512+cg*8+jj, n = gate*8+jj.
DEVI void gemm_x_tile(SMem& sm, const float* __restrict__ X,
                      const unsigned short* __restrict__ WxT,
                      const float* __restrict__ bg,
                      float* __restrict__ Zx2, int row0, int col0, int tid)
{
  const int lane = tid & 63, wave = tid >> 6;
  const int wr = wave >> 1, wc = wave & 1;
  const int m16 = lane & 15, kg = (lane >> 4) * 8;

  f32x4 acc[4][4] = {};

  for (int k0 = 0; k0 < 512; k0 += 32) {
    __syncthreads();
    #pragma unroll
    for (int i = 0; i < 4; ++i) {
      int idx = i * 256 + tid;
      int r = idx >> 3, kq = idx & 7;
      float4 v = *(const float4*)&X[(size_t)(row0 + r) * 512 + k0 + kq * 4];
      unsigned short* dst = &sm.g.Ash[r][kq * 4];
      dst[0] = f2bf(v.x); dst[1] = f2bf(v.y); dst[2] = f2bf(v.z); dst[3] = f2bf(v.w);
    }
    #pragma unroll
    for (int i = 0; i < 2; ++i) {
      int idx = i * 256 + tid;
      int c = idx >> 2, kq = idx & 3;
      *(uint4*)&sm.g.Bsh[c][kq * 8] =
          *(const uint4*)&WxT[(size_t)(col0 + c) * 512 + k0 + kq * 8];
    }
    __syncthreads();
    bf16x8 fa[4], fb[4];
    #pragma unroll
    for (int mi = 0; mi < 4; ++mi) fa[mi] = *(const bf16x8*)&sm.g.Ash[wr*64 + mi*16 + m16][kg];
    #pragma unroll
    for (int ni = 0; ni < 4; ++ni) fb[ni] = *(const bf16x8*)&sm.g.Bsh[wc*64 + ni*16 + m16][kg];
    #pragma unroll
    for (int mi = 0; mi < 4; ++mi)
      #pragma unroll
      for (int ni = 0; ni < 4; ++ni)
        acc[mi][ni] = __builtin_amdgcn_mfma_f32_16x16x32_bf16(fa[mi], fb[ni], acc[mi][ni], 0, 0, 0);
  }
  const int rg = (lane >> 4) * 4;
  #pragma unroll
  for (int ni = 0; ni < 4; ++ni) {
    int col = col0 + wc*64 + ni*16 + m16;
    float bb = bg[col];
    int gate = col >> 9, hcol = col & 511;
    int cg = hcol >> 3, n = gate * 8 + (hcol & 7);
    #pragma unroll
    for (int mi = 0; mi < 4; ++mi)
      #pragma unroll
      for (int r = 0; r < 4; ++r) {
        int row = row0 + wr*64 + mi*16 + rg + r;
        Zx2[((size_t)cg * 2048 + row) * 32 + n] = acc[mi][ni][r] + bb;
      }
  }
}

// ---------------------------------------------------------------- gemm_x (standalone, chunk 0)
__global__ __launch_bounds__(256) void gemm_x_kernel(
    const float* __restrict__ X, const unsigned short* __restrict__ WxT,
    const float* __restrict__ bg, float* __restrict__ Zx2)
{
  __shared__ SMem sm;
  gemm_x_tile(sm, X, WxT, bg, Zx2, blockIdx.x * 128, blockIdx.y * 128, threadIdx.x);
}

// ---------------------------------------------------------------- fused: rec (blk 0..63) + next-chunk gemm_x (blk 64..255)
__global__ __launch_bounds__(256, 1) void lstm_fused_kernel(
    const unsigned short* __restrict__ WhB,  // [64][32][512] bf16 swizzled
    const float* __restrict__ Zxcur,         // [64][2048][32] this chunk
    unsigned short* __restrict__ hsx,        // [513][64][512] bf16 history
    float* __restrict__ cbuf,                // [64][512] fp32
    int step0,
    unsigned int* __restrict__ flags,        // [64] wave-step counters (4 per block-step)
    float* __restrict__ dout,
    const float* __restrict__ Xnext,         // next chunk x (null on last)
    const unsigned short* __restrict__ WxT,
    const float* __restrict__ bg,
    float* __restrict__ Zxnext)              // next chunk Zx buffer
{
  __shared__ SMem sm;
  const int tid = threadIdx.x;

  if (blockIdx.x >= 64) {
    // ---------------- gemm role: compute Zx for chunk c+1 ----------------
    if (Xnext == nullptr) return;
    for (int tile = (int)blockIdx.x - 64; tile < 256; tile += 192) {
      gemm_x_tile(sm, Xnext, WxT, bg, Zxnext, (tile >> 4) * 128, (tile & 15) * 128, tid);
      __syncthreads();
    }
    return;
  }

  // ---------------- rec role ----------------
  const int cg = blockIdx.x;
  const int j0 = cg * 8;
  const int w   = tid >> 6;           // wave 0..3 -> batch rows w*16..+16
  const int l   = tid & 63;
  const int q   = l & 15;             // n-col within frag
  const int lg  = l >> 4;             // k-group
  const int jj  = q & 7;
  const int i0  = (q < 8) ? 0 : 2;    // acc rows this lane finishes

  // one-time: W slice -> LDS (linear copy; swizzle pre-applied by prep)
  {
    const uint4* wsrc = (const uint4*)(WhB + (size_t)cg * 32 * 512);
    uint4* wdst = (uint4*)sm.WT;
    #pragma unroll
    for (int i = 0; i < 8; ++i) wdst[i * 256 + tid] = wsrc[i * 256 + tid];
  }
  const size_t cidx = (size_t)(w * 16 + lg * 4 + i0) * 512 + j0 + jj;
  float c0r = cbuf[cidx];
  float c1r = cbuf[cidx + 512];
  __syncthreads();   // only barrier in rec role: W-in-LDS visible to all waves

  // Zx for t=0
  float zc0[4], zc1[4];
  {
    const float* zb = Zxcur + ((size_t)cg * 2048 + (w * 16 + lg * 4)) * 32 + q;
    #pragma unroll
    for (int i = 0; i < 4; ++i) { zc0[i] = zb[i * 32]; zc1[i] = zb[i * 32 + 16]; }
  }

  for (int t = 0; t < kT; ++t) {
    const int st = step0 + t;

    // -------- cheap gate: all waves poll the 64 wave-step counters.
    // flags[j] >= 4*st  <=>  block j has ISSUED its h stores for hsx[st].
    // (skip t=0: previous dispatch fully drained at the boundary)
    if (t > 0) {
      for (;;) {
        int fv = (int)__hip_atomic_load(&flags[l], __ATOMIC_RELAXED,
                                        __HIP_MEMORY_SCOPE_AGENT);
        if (__all(fv >= 4 * st)) break;
      }
    }

    // -------- A frags from global (16 x 16B of row w*16+q), sentinel-checked.
    // Flags say "issued"; the sentinel validates arrival. Retries are rare
    // (one extra ~RTT) since data was issued ~1 flag-RTT ago.
    const unsigned short* hrow =
        hsx + (size_t)st * (kN * kDH) + (w * 16 + q) * 512 + lg * 8;
    u32x4 av[16];
    int spin = 0;
    for (;;) {
      #pragma unroll
      for (int s = 0; s < 16; ++s) {
        asm volatile("global_load_dwordx4 %0, %1, off offset:%2 sc0 sc1"
                     : "=v"(av[s]) : "v"(hrow), "i"(64 * s));
      }
      asm volatile("s_waitcnt vmcnt(0)" ::: "memory");
      __builtin_amdgcn_sched_barrier(0);
      unsigned bad = 0;
      #pragma unroll
      for (int s = 0; s < 16; ++s) {
        bad |= ((av[s][0] & 0xFFFFu) == kSent);
        bad |= ((av[s][1] & 0xFFFFu) == kSent);
        bad |= ((av[s][2] & 0xFFFFu) == kSent);
        bad |= ((av[s][3] & 0xFFFFu) == kSent);
      }
      if (!__any(bad)) break;
      if (++spin > 64) {
        // rescue: guaranteed-coherent atomic loads (correctness net)
        const unsigned long long* hp = (const unsigned long long*)hrow;
        bad = 0;
        #pragma unroll
        for (int s = 0; s < 16; ++s) {
          union { unsigned long long q2[2]; u32x4 v4; } uu;
          uu.q2[0] = __hip_atomic_load(hp + 8 * s,     __ATOMIC_RELAXED,
                                       __HIP_MEMORY_SCOPE_AGENT);
          uu.q2[1] = __hip_atomic_load(hp + 8 * s + 1, __ATOMIC_RELAXED,
                                       __HIP_MEMORY_SCOPE_AGENT);
          av[s] = uu.v4;
          bad |= ((av[s][0] & 0xFFFFu) == kSent);
          bad |= ((av[s][1] & 0xFFFFu) == kSent);
          bad |= ((av[s][2] & 0xFFFFu) == kSent);
          bad |= ((av[s][3] & 0xFFFFu) == kSent);
        }
        if (!__any(bad)) break;
        spin = 65;   // stay on rescue cadence
      }
    }

    // Zx prefetch for t+1 issued BEFORE MFMA: completes under compute.
    float zn0[4], zn1[4];
    if (t + 1 < kT) {
      const float* zb = Zxcur +
          ((size_t)cg * 2048 + ((t + 1) * 64 + w * 16 + lg * 4)) * 32 + q;
      #pragma unroll
      for (int i = 0; i < 4; ++i) { zn0[i] = zb[i * 32]; zn1[i] = zb[i * 32 + 16]; }
    }

    // MFMA: 16 ksteps x 2 n-frags
    f32x4 acc0 = {}, acc1 = {};
    #pragma unroll
    for (int s = 0; s < 16; ++s) {
      const int kb = 4 * s + lg;
      bf16x8 b0 = *(const bf16x8*)&sm.WT[(size_t)q * 512 + ((kb ^ jj) << 3)];
      bf16x8 b1 = *(const bf16x8*)&sm.WT[(size_t)(16 + q) * 512 + ((kb ^ jj) << 3)];
      union { u32x4 u; bf16x8 a; } ua; ua.u = av[s];
      acc0 = __builtin_amdgcn_mfma_f32_16x16x32_bf16(ua.a, b0, acc0, 0, 0, 0);
      acc1 = __builtin_amdgcn_mfma_f32_16x16x32_bf16(ua.a, b1, acc1, 0, 0, 0);
    }

    // z = acc + Zx (own cols), then exchange with lane^8 to gather 4 gates
    float t0[4], t1[4], ot0[4], ot1[4];
    #pragma unroll
    for (int i = 0; i < 4; ++i) { t0[i] = acc0[i] + zc0[i]; t1[i] = acc1[i] + zc1[i]; }
    #pragma unroll
    for (int i = 0; i < 4; ++i) {
      ot0[i] = __shfl_xor(t0[i], 8, 64);
      ot1[i] = __shfl_xor(t1[i], 8, 64);
    }
    float hh[2];
    #pragma unroll
    for (int u = 0; u < 2; ++u) {
      const int i = i0 + u;
      float zf = (q < 8) ? t0[i] : ot0[i];
      float zc = (q < 8) ? ot0[i] : t0[i];
      float zi = (q < 8) ? t1[i] : ot1[i];
      float zo = (q < 8) ? ot1[i] : t1[i];
      float fg = sigm(zf), ig = sigm(zi), og = sigm(zo);
      float Ct = tanh_f(zc);
      float& cr = u ? c1r : c0r;
      cr = fg * cr + ig * Ct;
      hh[u] = og * tanh_f(cr);
    }

    // store h (bf16 pairs packed per dword => halves land together)
    {
      unsigned short hb0 = f2bf(hh[0]), hb1 = f2bf(hh[1]);
      unsigned o0 = (unsigned)(unsigned short)__shfl_xor((int)hb0, 1, 64);
      unsigned o1 = (unsigned)(unsigned short)__shfl_xor((int)hb1, 1, 64);
      if ((q & 1) == 0) {
        const size_t base = (size_t)(st + 1) * (kN * kDH) +
                            (size_t)(w * 16 + lg * 4 + i0) * 512 + j0 + jj;
        __hip_atomic_store((unsigned*)&hsx[base], ((unsigned)hb0) | (o0 << 16),
                           __ATOMIC_RELAXED, __HIP_MEMORY_SCOPE_AGENT);
        __hip_atomic_store((unsigned*)&hsx[base + 512], ((unsigned)hb1) | (o1 << 16),
                           __ATOMIC_RELAXED, __HIP_MEMORY_SCOPE_AGENT);
      }
      if (st == kL - 1) {
        dout[kOutSz + cidx] = hh[0];
        dout[kOutSz + cidx + 512] = hh[1];
        dout[kOutSz + (size_t)kN * kDH + cidx] = c0r;
        dout[kOutSz + (size_t)kN * kDH + cidx + 512] = c1r;
      }
    }

    // publish: per-wave counter bump, NO drain, NO barrier. Compiler fence
    // keeps issue order store->add; HW reordering is covered by the sentinel.
    asm volatile("" ::: "memory");
    if (l == 0)
      __hip_atomic_fetch_add(&flags[cg], 1u, __ATOMIC_RELAXED,
                             __HIP_MEMORY_SCOPE_AGENT);

    if (t + 1 < kT) {
      #pragma unroll
      for (int i = 0; i < 4; ++i) { zc0[i] = zn0[i]; zc1[i] = zn1[i]; }
    }
  }

  cbuf[cidx] = c0r;
  cbuf[cidx + 512] = c1r;
}

// ---------------------------------------------------------------- gemm_out
__global__ __launch_bounds__(256) void gemm_out_kernel(
    const unsigned short* __restrict__ Hs,   // [32768][512] bf16 (h_1..h_512)
    const unsigned short* __restrict__ WoT,  // [512][512] bf16 (B^T)
    const float* __restrict__ bout,
    float* __restrict__ out)                 // [32768][512] fp32
{
  __shared__ unsigned short Ash[128][40];
  __shared__ unsigned short Bsh[128][40];
  const int row0 = blockIdx.x * 128, col0 = blockIdx.y * 128;
  const int tid = threadIdx.x;
  const int lane = tid & 63, wave = tid >> 6;
  const int wr = wave >> 1, wc = wave & 1;
  const int m16 = lane & 15, kg = (lane >> 4) * 8;

  f32x4 acc[4][4] = {};

  for (int k0 = 0; k0 < 512; k0 += 32) {
    __syncthreads();
    #pragma unroll
    for (int i = 0; i < 2; ++i) {
      int idx = i * 256 + tid;
      int r = idx >> 2, kq = idx & 3;
      *(uint4*)&Ash[r][kq * 8] =
          *(const uint4*)&Hs[(size_t)(row0 + r) * 512 + k0 + kq * 8];
    }
    #pragma unroll
    for (int i = 0; i < 2; ++i) {
      int idx = i * 256 + tid;
      int c = idx >> 2, kq = idx & 3;
      *(uint4*)&Bsh[c][kq * 8] =
          *(const uint4*)&WoT[(size_t)(col0 + c) * 512 + k0 + kq * 8];
    }
    __syncthreads();
    bf16x8 fa[4], fb[4];
    #pragma unroll
    for (int mi = 0; mi < 4; ++mi) fa[mi] = *(const bf16x8*)&Ash[wr*64 + mi*16 + m16][kg];
    #pragma unroll
    for (int ni = 0; ni < 4; ++ni) fb[ni] = *(const bf16x8*)&Bsh[wc*64 + ni*16 + m16][kg];
    #pragma unroll
    for (int mi = 0; mi < 4; ++mi)
      #pragma unroll
      for (int ni = 0; ni < 4; ++ni)
        acc[mi][ni] = __builtin_amdgcn_mfma_f32_16x16x32_bf16(fa[mi], fb[ni], acc[mi][ni], 0, 0, 0);
  }
  const int rg = (lane >> 4) * 4;
  #pragma unroll
  for (int ni = 0; ni < 4; ++ni) {
    int col = col0 + wc*64 + ni*16 + m16;
    float bb = bout[col];
    #pragma unroll
    for (int mi = 0; mi < 4; ++mi)
      #pragma unroll
      for (int r = 0; r < 4; ++r)
        out[(size_t)(row0 + wr*64 + mi*16 + rg + r) * 512 + col] = acc[mi][ni][r] + bb;
  }
}

// ---------------------------------------------------------------- launch
extern "C" void kernel_launch(void* const* d_in, const int* in_sizes, int n_in,
                              void* d_out, int out_size, void* d_ws, size_t ws_size,
                              hipStream_t stream) {
  (void)in_sizes; (void)n_in; (void)out_size; (void)ws_size;
  const float* x    = (const float*)d_in[0];
  const float* h0   = (const float*)d_in[1];
  const float* c0   = (const float*)d_in[2];
  const float* Wf   = (const float*)d_in[3];
  const float* bf_  = (const float*)d_in[4];
  const float* Wc   = (const float*)d_in[5];
  const float* bc_  = (const float*)d_in[6];
  const float* Wi_  = (const float*)d_in[7];
  const float* bi_  = (const float*)d_in[8];
  const float* Wo   = (const float*)d_in[9];
  const float* bo_  = (const float*)d_in[10];
  const float* Wout = (const float*)d_in[11];
  const float* bout = (const float*)d_in[12];
  float* out = (float*)d_out;

  char* ws = (char*)d_ws;
  size_t off = 0;
  auto alloc = [&](size_t bytes) -> void* {
    void* p = ws + off;
    off += (bytes + 255) & ~(size_t)255;
    return p;
  };
  float*          ZxA = (float*)alloc((size_t)kT * kN * kG * 4);                 // 16 MB
  float*          ZxB = (float*)alloc((size_t)kT * kN * kG * 4);                 // 16 MB
  unsigned short* hsx = (unsigned short*)alloc((size_t)(kL + 1) * kN * kDH * 2); // 33.6 MB
  unsigned short* WxT = (unsigned short*)alloc((size_t)kG * 512 * 2);            // 2 MB
  unsigned short* WoT = (unsigned short*)alloc((size_t)512 * 512 * 2);           // 0.5 MB
  unsigned short* WhB = (unsigned short*)alloc((size_t)64 * 32 * 512 * 2);       // 2 MB
  float*          bg  = (float*)alloc((size_t)kG * 4);
  float*          cbf = (float*)alloc((size_t)kN * kDH * 4);
  unsigned int*   flg = (unsigned int*)alloc(256);

  prep_kernel<<<1024, 256, 0, stream>>>(Wf, Wc, Wi_, Wo, bf_, bc_, bi_, bo_,
                                        Wout, h0, c0, WxT, WoT, WhB, bg, hsx, cbf, flg);
  // chunk 0's Zx
  gemm_x_kernel<<<dim3(16, 16), 256, 0, stream>>>(x, WxT, bg, ZxA);
  for (int c = 0; c < kChunks; ++c) {
    float* Zxcur = (c & 1) ? ZxB : ZxA;
    float* Zxnxt = (c & 1) ? ZxA : ZxB;
    const float* xnext = (c + 1 < kChunks)
        ? x + (size_t)(c + 1) * kT * kN * kDIN : nullptr;
    lstm_fused_kernel<<<256, 256, 0, stream>>>(
        WhB, Zxcur, hsx, cbf, c * kT, flg, out, xnext, WxT, bg, Zxnxt);
  }
  gemm_out_kernel<<<dim3(256, 4), 256, 0, stream>>>(
      hsx + (size_t)kN * kDH, WoT, bout, out);
}

// Round 5
// 4023.999 us; speedup vs baseline: 10.6253x; 1.4459x over previous
//
#include <hip/hip_runtime.h>

typedef float  f32x4  __attribute__((ext_vector_type(4)));
typedef short  bf16x8 __attribute__((ext_vector_type(8)));

#define DEVI static __device__ __forceinline__

namespace {
constexpr int kL   = 512;
constexpr int kN   = 64;
constexpr int kDH  = 512;
constexpr int kDIN = 512;
constexpr int kG   = 2048;            // 4*kDH
constexpr int kT   = 32;              // timesteps per chunk (fallback path)
constexpr int kChunks = kL / kT;      // 16
constexpr size_t kOutSz = (size_t)kL * kN * kDIN;  // 16,777,216 floats
// workspace need for the full-Zx path (all 256-aligned):
constexpr size_t kFullNeed =
    (size_t)268435456 /*ZxFull*/ + 33619968 /*hsx*/ + 2097152 /*WxT*/ +
    524288 /*WoT*/ + 2097152 /*WhB*/ + 8192 /*bg*/ + 131072 /*cbf*/ + 1024 /*flg*/;
}

DEVI unsigned short f2bf(float f) {
  union { float f; unsigned u; } v; v.f = f;
  unsigned r = v.u + 0x7FFFu + ((v.u >> 16) & 1u);   // RNE
  return (unsigned short)(r >> 16);
}
DEVI float sigm(float z) { return 1.f / (1.f + __expf(-z)); }
DEVI float tanh_f(float z) { return 2.f / (1.f + __expf(-2.f * z)) - 1.f; }

// ---------------------------------------------------------------- prep
__global__ void prep_kernel(
    const float* __restrict__ Wf, const float* __restrict__ Wc,
    const float* __restrict__ Wi, const float* __restrict__ Wo,
    const float* __restrict__ bf, const float* __restrict__ bc,
    const float* __restrict__ bi, const float* __restrict__ bo,
    const float* __restrict__ Wout,
    const float* __restrict__ h0, const float* __restrict__ c0,
    unsigned short* __restrict__ WxT, unsigned short* __restrict__ WoT,
    unsigned short* __restrict__ WhB, float* __restrict__ bg,
    unsigned short* __restrict__ hsx, float* __restrict__ cbuf,
    unsigned int* __restrict__ flags)
{
  const int gid = blockIdx.x * blockDim.x + threadIdx.x;
  const int stride = gridDim.x * blockDim.x;
  const float* Wg[4]  = {Wf, Wc, Wi, Wo};
  const float* bgs[4] = {bf, bc, bi, bo};

  // per-wave-plane flags: flags[w*64 + cg], w=0..3, cg=0..63
  for (int i = gid; i < 256; i += stride) flags[i] = 0u;

  for (int i = gid; i < kG * 512; i += stride) {
    int k = i >> 11, g = i & 2047;
    WxT[(size_t)g * 512 + k] = f2bf(Wg[g >> 9][(size_t)k * 512 + (g & 511)]);
  }
  for (int i = gid; i < 512 * 512; i += stride) {
    int k = i >> 9, c = i & 511;
    WoT[(size_t)c * 512 + k] = f2bf(Wout[(size_t)k * 512 + c]);
  }
  // WhB: i = k*1024 + gate*512 + hcol  -> coalesced source reads
  for (int i = gid; i < 4 * 512 * 512; i += stride) {
    int hcol = i & 511;
    int gate = (i >> 9) & 3;
    int k    = i >> 11;
    int cg = hcol >> 3, jj = hcol & 7;
    int n  = gate * 8 + jj;
    int kblk = k >> 3, kin = k & 7;
    size_t dst = ((size_t)cg * 32 + n) * 512 + (((kblk ^ (n & 7)) << 3) | kin);
    WhB[dst] = f2bf(Wg[gate][(size_t)(512 + k) * 512 + hcol]);
  }
  for (int i = gid; i < kG; i += stride) bg[i] = bgs[i >> 9][i & 511];
  for (int i = gid; i < kN * kDH; i += stride) {
    hsx[i]  = f2bf(h0[i]);   // hsx[0] = h0
    cbuf[i] = c0[i];
  }
}

// Shared-memory for the gemm kernels.
struct SMem {
  struct { unsigned short Ash[128][40]; unsigned short Bsh[128][40]; } g;  // 20 KB
};

// ---------------------------------------------------------------- gemm_x body
// Zx2[cg][row][n] = x_row . Wx[:,col] + bg[col]; col = gate*512+cg*8+jj, n = gate*8+jj.
// nrows = number of rows in the Zx2 buffer (32768 full-path, 2048 chunked).
DEVI void gemm_x_tile(SMem& sm, const float* __restrict__ X,
                      const unsigned short* __restrict__ WxT,
                      const float* __restrict__ bg,
                      float* __restrict__ Zx2, int nrows,
                      int row0, int col0, int tid)
{
  const int lane = tid & 63, wave = tid >> 6;
  const int wr = wave >> 1, wc = wave & 1;
  const int m16 = lane & 15, kg = (lane >> 4) * 8;

  f32x4 acc[4][4] = {};

  for (int k0 = 0; k0 < 512; k0 += 32) {
    __syncthreads();
    #pragma unroll
    for (int i = 0; i < 4; ++i) {
      int idx = i * 256 + tid;
      int r = idx >> 3, kq = idx & 7;
      float4 v = *(const float4*)&X[(size_t)(row0 + r) * 512 + k0 + kq * 4];
      unsigned short* dst = &sm.g.Ash[r][kq * 4];
      dst[0] = f2bf(v.x); dst[1] = f2bf(v.y); dst[2] = f2bf(v.z); dst[3] = f2bf(v.w);
    }
    #pragma unroll
    for (int i = 0; i < 2; ++i) {
      int idx = i * 256 + tid;
      int c = idx >> 2, kq = idx & 3;
      *(uint4*)&sm.g.Bsh[c][kq * 8] =
          *(const uint4*)&WxT[(size_t)(col0 + c) * 512 + k0 + kq * 8];
    }
    __syncthreads();
    bf16x8 fa[4], fb[4];
    #pragma unroll
    for (int mi = 0; mi < 4; ++mi) fa[mi] = *(const bf16x8*)&sm.g.Ash[wr*64 + mi*16 + m16][kg];
    #pragma unroll
    for (int ni = 0; ni < 4; ++ni) fb[ni] = *(const bf16x8*)&sm.g.Bsh[wc*64 + ni*16 + m16][kg];
    #pragma unroll
    for (int mi = 0; mi < 4; ++mi)
      #pragma unroll
      for (int ni = 0; ni < 4; ++ni)
        acc[mi][ni] = __builtin_amdgcn_mfma_f32_16x16x32_bf16(fa[mi], fb[ni], acc[mi][ni], 0, 0, 0);
  }
  const int rg = (lane >> 4) * 4;
  #pragma unroll
  for (int ni = 0; ni < 4; ++ni) {
    int col = col0 + wc*64 + ni*16 + m16;
    float bb = bg[col];
    int gate = col >> 9, hcol = col & 511;
    int cg = hcol >> 3, n = gate * 8 + (hcol & 7);
    #pragma unroll
    for (int mi = 0; mi < 4; ++mi)
      #pragma unroll
      for (int r = 0; r < 4; ++r) {
        int row = row0 + wr*64 + mi*16 + rg + r;
        Zx2[((size_t)cg * nrows + row) * 32 + n] = acc[mi][ni][r] + bb;
      }
  }
}

__global__ __launch_bounds__(256) void gemm_x_kernel(
    const float* __restrict__ X, const unsigned short* __restrict__ WxT,
    const float* __restrict__ bg, float* __restrict__ Zx2, int nrows)
{
  __shared__ SMem sm;
  gemm_x_tile(sm, X, WxT, bg, Zx2, nrows, blockIdx.x * 128, blockIdx.y * 128,
              threadIdx.x);
}

// ---------------------------------------------------------------- rec kernel
// Persistent (nsteps=512 full path) or per-chunk (nsteps=32 fallback).
// Wave-plane decomposition: wave w of block cg produces h rows w*16..+15,
// cols cg*8..+7, and consumes ONLY rows w*16..+15 of step st-1. Protocol
// (validated in R1's isolated dispatch at ~3.3 us/step): store h ->
// per-wave vmcnt(0) drain -> publish flags[w*64+cg]=st+1; consumer polls
// its plane's 64 flags. No __syncthreads in the step loop.
__global__ __launch_bounds__(256, 1) void lstm_rec_kernel(
    const unsigned short* __restrict__ WhB,  // [64][32][512] bf16 swizzled
    const float* __restrict__ Zx,            // [64][zx_nrows][32]
    int zx_nrows,
    unsigned short* __restrict__ hsx,        // [513][64][512] bf16 history
    float* __restrict__ cbuf,                // [64][512] fp32
    int step0, int nsteps,
    unsigned int* __restrict__ flags,        // [4][64] per-plane
    float* __restrict__ dout)
{
  __shared__ unsigned short WT[32 * 512];    // 32 KB
  const int tid = threadIdx.x;
  const int cg  = blockIdx.x;
  const int j0  = cg * 8;
  const int w   = tid >> 6;           // wave 0..3 -> batch rows w*16..+16
  const int l   = tid & 63;
  const int q   = l & 15;             // n-col within frag
  const int lg  = l >> 4;             // k-group
  const int jj  = q & 7;
  const int i0  = (q < 8) ? 0 : 2;    // acc rows this lane finishes

  // one-time: W slice -> LDS (linear copy; swizzle pre-applied by prep)
  {
    const uint4* wsrc = (const uint4*)(WhB + (size_t)cg * 32 * 512);
    uint4* wdst = (uint4*)WT;
    #pragma unroll
    for (int i = 0; i < 8; ++i) wdst[i * 256 + tid] = wsrc[i * 256 + tid];
  }
  const size_t cidx = (size_t)(w * 16 + lg * 4 + i0) * 512 + j0 + jj;
  float c0r = cbuf[cidx];
  float c1r = cbuf[cidx + 512];
  __syncthreads();   // only barrier: W-in-LDS visible to all waves

  // Zx for t=0
  float zc0[4], zc1[4];
  {
    const float* zb = Zx + ((size_t)cg * zx_nrows + (w * 16 + lg * 4)) * 32 + q;
    #pragma unroll
    for (int i = 0; i < 4; ++i) { zc0[i] = zb[i * 32]; zc1[i] = zb[i * 32 + 16]; }
  }

  unsigned int* fbase = flags + w * 64;   // this plane's flags

  for (int t = 0; t < nsteps; ++t) {
    const int st = step0 + t;

    // wait for this plane's hsx rows at step st (st=0: h0 ready from prep).
    // All 64 lanes poll; lane l watches block l's plane-w flag.
    if (st > 0) {
      for (;;) {
        int fv = (int)__hip_atomic_load(&fbase[l], __ATOMIC_RELAXED,
                                        __HIP_MEMORY_SCOPE_AGENT);
        if (__all(fv >= st)) break;
      }
      asm volatile("" ::: "memory");   // keep A-loads below the poll
    }

    // A-frags direct from global: lane: row w*16+q, k = 32s + lg*8 ..+8
    const unsigned short* hrow =
        hsx + (size_t)st * (kN * kDH) + (w * 16 + q) * 512 + lg * 8;
    bf16x8 A[16];
    #pragma unroll
    for (int s = 0; s < 16; ++s) A[s] = *(const bf16x8*)(hrow + 32 * s);

    // Zx prefetch for t+1 issued BEFORE MFMA: completes under compute.
    float zn0[4], zn1[4];
    if (t + 1 < nsteps) {
      const float* zb = Zx +
          ((size_t)cg * zx_nrows + ((t + 1) * 64 + w * 16 + lg * 4)) * 32 + q;
      #pragma unroll
      for (int i = 0; i < 4; ++i) { zn0[i] = zb[i * 32]; zn1[i] = zb[i * 32 + 16]; }
    }

    // MFMA: 16 ksteps x 2 n-frags
    f32x4 acc0 = {}, acc1 = {};
    #pragma unroll
    for (int s = 0; s < 16; ++s) {
      const int kb = 4 * s + lg;
      bf16x8 b0 = *(const bf16x8*)&WT[(size_t)q * 512 + ((kb ^ jj) << 3)];
      bf16x8 b1 = *(const bf16x8*)&WT[(size_t)(16 + q) * 512 + ((kb ^ jj) << 3)];
      acc0 = __builtin_amdgcn_mfma_f32_16x16x32_bf16(A[s], b0, acc0, 0, 0, 0);
      acc1 = __builtin_amdgcn_mfma_f32_16x16x32_bf16(A[s], b1, acc1, 0, 0, 0);
    }

    // z = acc + Zx (own cols), then exchange with lane^8 to gather 4 gates
    float t0[4], t1[4], ot0[4], ot1[4];
    #pragma unroll
    for (int i = 0; i < 4; ++i) { t0[i] = acc0[i] + zc0[i]; t1[i] = acc1[i] + zc1[i]; }
    #pragma unroll
    for (int i = 0; i < 4; ++i) {
      ot0[i] = __shfl_xor(t0[i], 8, 64);
      ot1[i] = __shfl_xor(t1[i], 8, 64);
    }
    float hh[2];
    #pragma unroll
    for (int u = 0; u < 2; ++u) {
      const int i = i0 + u;
      float zf = (q < 8) ? t0[i] : ot0[i];
      float zc = (q < 8) ? ot0[i] : t0[i];
      float zi = (q < 8) ? t1[i] : ot1[i];
      float zo = (q < 8) ? ot1[i] : t1[i];
      float fg = sigm(zf), ig = sigm(zi), og = sigm(zo);
      float Ct = tanh_f(zc);
      float& cr = u ? c1r : c0r;
      cr = fg * cr + ig * Ct;
      hh[u] = og * tanh_f(cr);
    }

    // store h (bf16 pairs packed per dword, agent-scope write-through)
    {
      unsigned short hb0 = f2bf(hh[0]), hb1 = f2bf(hh[1]);
      unsigned o0 = (unsigned)(unsigned short)__shfl_xor((int)hb0, 1, 64);
      unsigned o1 = (unsigned)(unsigned short)__shfl_xor((int)hb1, 1, 64);
      if ((q & 1) == 0) {
        const size_t base = (size_t)(st + 1) * (kN * kDH) +
                            (size_t)(w * 16 + lg * 4 + i0) * 512 + j0 + jj;
        __hip_atomic_store((unsigned*)&hsx[base], ((unsigned)hb0) | (o0 << 16),
                           __ATOMIC_RELAXED, __HIP_MEMORY_SCOPE_AGENT);
        __hip_atomic_store((unsigned*)&hsx[base + 512], ((unsigned)hb1) | (o1 << 16),
                           __ATOMIC_RELAXED, __HIP_MEMORY_SCOPE_AGENT);
      }
      if (st == kL - 1) {
        dout[kOutSz + cidx] = hh[0];
        dout[kOutSz + cidx + 512] = hh[1];
        dout[kOutSz + (size_t)kN * kDH + cidx] = c0r;
        dout[kOutSz + (size_t)kN * kDH + cidx + 512] = c1r;
      }
    }

    // drain THIS wave's h stores (per-wave vmcnt), then publish plane flag
    asm volatile("s_waitcnt vmcnt(0)" ::: "memory");
    if (l == 0)
      __hip_atomic_store(&fbase[cg], (unsigned)(st + 1), __ATOMIC_RELAXED,
                         __HIP_MEMORY_SCOPE_AGENT);

    if (t + 1 < nsteps) {
      #pragma unroll
      for (int i = 0; i < 4; ++i) { zc0[i] = zn0[i]; zc1[i] = zn1[i]; }
    }
  }

  cbuf[cidx] = c0r;
  cbuf[cidx + 512] = c1r;
}

// ---------------------------------------------------------------- gemm_out
__global__ __launch_bounds__(256) void gemm_out_kernel(
    const unsigned short* __restrict__ Hs,   // [32768][512] bf16 (h_1..h_512)
    const unsigned short* __restrict__ WoT,  // [512][512] bf16 (B^T)
    const float* __restrict__ bout,
    float* __restrict__ out)                 // [32768][512] fp32
{
  __shared__ unsigned short Ash[128][40];
  __shared__ unsigned short Bsh[128][40];
  const int row0 = blockIdx.x * 128, col0 = blockIdx.y * 128;
  const int tid = threadIdx.x;
  const int lane = tid & 63, wave = tid >> 6;
  const int wr = wave >> 1, wc = wave & 1;
  const int m16 = lane & 15, kg = (lane >> 4) * 8;

  f32x4 acc[4][4] = {};

  for (int k0 = 0; k0 < 512; k0 += 32) {
    __syncthreads();
    #pragma unroll
    for (int i = 0; i < 2; ++i) {
      int idx = i * 256 + tid;
      int r = idx >> 2, kq = idx & 3;
      *(uint4*)&Ash[r][kq * 8] =
          *(const uint4*)&Hs[(size_t)(row0 + r) * 512 + k0 + kq * 8];
    }
    #pragma unroll
    for (int i = 0; i < 2; ++i) {
      int idx = i * 256 + tid;
      int c = idx >> 2, kq = idx & 3;
      *(uint4*)&Bsh[c][kq * 8] =
          *(const uint4*)&WoT[(size_t)(col0 + c) * 512 + k0 + kq * 8];
    }
    __syncthreads();
    bf16x8 fa[4], fb[4];
    #pragma unroll
    for (int mi = 0; mi < 4; ++mi) fa[mi] = *(const bf16x8*)&Ash[wr*64 + mi*16 + m16][kg];
    #pragma unroll
    for (int ni = 0; ni < 4; ++ni) fb[ni] = *(const bf16x8*)&Bsh[wc*64 + ni*16 + m16][kg];
    #pragma unroll
    for (int mi = 0; mi < 4; ++mi)
      #pragma unroll
      for (int ni = 0; ni < 4; ++ni)
        acc[mi][ni] = __builtin_amdgcn_mfma_f32_16x16x32_bf16(fa[mi], fb[ni], acc[mi][ni], 0, 0, 0);
  }
  const int rg = (lane >> 4) * 4;
  #pragma unroll
  for (int ni = 0; ni < 4; ++ni) {
    int col = col0 + wc*64 + ni*16 + m16;
    float bb = bout[col];
    #pragma unroll
    for (int mi = 0; mi < 4; ++mi)
      #pragma unroll
      for (int r = 0; r < 4; ++r)
        out[(size_t)(row0 + wr*64 + mi*16 + rg + r) * 512 + col] = acc[mi][ni][r] + bb;
  }
}

// ---------------------------------------------------------------- launch
extern "C" void kernel_launch(void* const* d_in, const int* in_sizes, int n_in,
                              void* d_out, int out_size, void* d_ws, size_t ws_size,
                              hipStream_t stream) {
  (void)in_sizes; (void)n_in; (void)out_size;
  const float* x    = (const float*)d_in[0];
  const float* h0   = (const float*)d_in[1];
  const float* c0   = (const float*)d_in[2];
  const float* Wf   = (const float*)d_in[3];
  const float* bf_  = (const float*)d_in[4];
  const float* Wc   = (const float*)d_in[5];
  const float* bc_  = (const float*)d_in[6];
  const float* Wi_  = (const float*)d_in[7];
  const float* bi_  = (const float*)d_in[8];
  const float* Wo   = (const float*)d_in[9];
  const float* bo_  = (const float*)d_in[10];
  const float* Wout = (const float*)d_in[11];
  const float* bout = (const float*)d_in[12];
  float* out = (float*)d_out;

  char* ws = (char*)d_ws;
  size_t off = 0;
  auto alloc = [&](size_t bytes) -> void* {
    void* p = ws + off;
    off += (bytes + 255) & ~(size_t)255;
    return p;
  };

  const bool big = (ws_size >= kFullNeed);

  if (big) {
    // -------- full-Zx path: one big gemm, one persistent rec dispatch --------
    float*          ZxF = (float*)alloc((size_t)kL * kN * kG * 4);               // 256 MB
    unsigned short* hsx = (unsigned short*)alloc((size_t)(kL + 1) * kN * kDH * 2);
    unsigned short* WxT = (unsigned short*)alloc((size_t)kG * 512 * 2);
    unsigned short* WoT = (unsigned short*)alloc((size_t)512 * 512 * 2);
    unsigned short* WhB = (unsigned short*)alloc((size_t)64 * 32 * 512 * 2);
    float*          bg  = (float*)alloc((size_t)kG * 4);
    float*          cbf = (float*)alloc((size_t)kN * kDH * 4);
    unsigned int*   flg = (unsigned int*)alloc(1024);

    prep_kernel<<<1024, 256, 0, stream>>>(Wf, Wc, Wi_, Wo, bf_, bc_, bi_, bo_,
                                          Wout, h0, c0, WxT, WoT, WhB, bg, hsx,
                                          cbf, flg);
    gemm_x_kernel<<<dim3(256, 16), 256, 0, stream>>>(x, WxT, bg, ZxF,
                                                     kL * kN /*32768 rows*/);
    lstm_rec_kernel<<<64, 256, 0, stream>>>(WhB, ZxF, kL * kN, hsx, cbf,
                                            0, kL, flg, out);
    gemm_out_kernel<<<dim3(256, 4), 256, 0, stream>>>(
        hsx + (size_t)kN * kDH, WoT, bout, out);
  } else {
    // -------- fallback: chunked double-buffer, serial gemm_x per chunk --------
    float*          ZxA = (float*)alloc((size_t)kT * kN * kG * 4);               // 16 MB
    float*          ZxB = (float*)alloc((size_t)kT * kN * kG * 4);               // 16 MB
    unsigned short* hsx = (unsigned short*)alloc((size_t)(kL + 1) * kN * kDH * 2);
    unsigned short* WxT = (unsigned short*)alloc((size_t)kG * 512 * 2);
    unsigned short* WoT = (unsigned short*)alloc((size_t)512 * 512 * 2);
    unsigned short* WhB = (unsigned short*)alloc((size_t)64 * 32 * 512 * 2);
    float*          bg  = (float*)alloc((size_t)kG * 4);
    float*          cbf = (float*)alloc((size_t)kN * kDH * 4);
    unsigned int*   flg = (unsigned int*)alloc(1024);

    prep_kernel<<<1024, 256, 0, stream>>>(Wf, Wc, Wi_, Wo, bf_, bc_, bi_, bo_,
                                          Wout, h0, c0, WxT, WoT, WhB, bg, hsx,
                                          cbf, flg);
    gemm_x_kernel<<<dim3(16, 16), 256, 0, stream>>>(x, WxT, bg, ZxA, kT * kN);
    for (int c = 0; c < kChunks; ++c) {
      float* Zxcur = (c & 1) ? ZxB : ZxA;
      float* Zxnxt = (c & 1) ? ZxA : ZxB;
      lstm_rec_kernel<<<64, 256, 0, stream>>>(WhB, Zxcur, kT * kN, hsx, cbf,
                                              c * kT, kT, flg, out);
      if (c + 1 < kChunks) {
        const float* xnext = x + (size_t)(c + 1) * kT * kN * kDIN;
        gemm_x_kernel<<<dim3(16, 16), 256, 0, stream>>>(xnext, WxT, bg, Zxnxt,
                                                        kT * kN);
      }
    }
    gemm_out_kernel<<<dim3(256, 4), 256, 0, stream>>>(
        hsx + (size_t)kN * kDH, WoT, bout, out);
  }
}

// Round 6
// 3560.421 us; speedup vs baseline: 12.0088x; 1.1302x over previous
//
#include <hip/hip_runtime.h>

typedef float  f32x4  __attribute__((ext_vector_type(4)));
typedef short  bf16x8 __attribute__((ext_vector_type(8)));

#define DEVI static __device__ __forceinline__

namespace {
constexpr int kL   = 512;
constexpr int kN   = 64;
constexpr int kDH  = 512;
constexpr int kDIN = 512;
constexpr int kG   = 2048;            // 4*kDH
constexpr int kT   = 32;              // timesteps per chunk
constexpr int kChunks = kL / kT;      // 16
constexpr size_t kOutSz = (size_t)kL * kN * kDIN;  // 16,777,216 floats
}

DEVI unsigned short f2bf(float f) {
  union { float f; unsigned u; } v; v.f = f;
  unsigned r = v.u + 0x7FFFu + ((v.u >> 16) & 1u);   // RNE
  return (unsigned short)(r >> 16);
}
DEVI float sigm(float z) { return 1.f / (1.f + __expf(-z)); }
DEVI float tanh_f(float z) { return 2.f / (1.f + __expf(-2.f * z)) - 1.f; }

// ---------------------------------------------------------------- prep
__global__ void prep_kernel(
    const float* __restrict__ Wf, const float* __restrict__ Wc,
    const float* __restrict__ Wi, const float* __restrict__ Wo,
    const float* __restrict__ bf, const float* __restrict__ bc,
    const float* __restrict__ bi, const float* __restrict__ bo,
    const float* __restrict__ Wout,
    const float* __restrict__ h0, const float* __restrict__ c0,
    unsigned short* __restrict__ WxT, unsigned short* __restrict__ WoT,
    unsigned short* __restrict__ WhB, float* __restrict__ bg,
    unsigned short* __restrict__ hsx, float* __restrict__ cbuf,
    unsigned int* __restrict__ cnt)
{
  const int gid = blockIdx.x * blockDim.x + threadIdx.x;
  const int stride = gridDim.x * blockDim.x;
  const float* Wg[4]  = {Wf, Wc, Wi, Wo};
  const float* bgs[4] = {bf, bc, bi, bo};

  // per-step aggregate counters: cnt[st]==256 <=> all 256 producer waves
  // have drained their h stores for hsx[st].
  for (int i = gid; i < kL + 1; i += stride) cnt[i] = 0u;

  for (int i = gid; i < kG * 512; i += stride) {
    int k = i >> 11, g = i & 2047;
    WxT[(size_t)g * 512 + k] = f2bf(Wg[g >> 9][(size_t)k * 512 + (g & 511)]);
  }
  for (int i = gid; i < 512 * 512; i += stride) {
    int k = i >> 9, c = i & 511;
    WoT[(size_t)c * 512 + k] = f2bf(Wout[(size_t)k * 512 + c]);
  }
  // WhB: i = k*1024 + gate*512 + hcol  -> coalesced source reads
  for (int i = gid; i < 4 * 512 * 512; i += stride) {
    int hcol = i & 511;
    int gate = (i >> 9) & 3;
    int k    = i >> 11;
    int cg = hcol >> 3, jj = hcol & 7;
    int n  = gate * 8 + jj;
    int kblk = k >> 3, kin = k & 7;
    size_t dst = ((size_t)cg * 32 + n) * 512 + (((kblk ^ (n & 7)) << 3) | kin);
    WhB[dst] = f2bf(Wg[gate][(size_t)(512 + k) * 512 + hcol]);
  }
  for (int i = gid; i < kG; i += stride) bg[i] = bgs[i >> 9][i & 511];
  for (int i = gid; i < kN * kDH; i += stride) {
    hsx[i]  = f2bf(h0[i]);   // hsx[0] = h0
    cbuf[i] = c0[i];
  }
}

// Shared-memory overlay for the fused kernel's two roles.
struct SMem {
  union {
    unsigned short WT[32 * 512];                                   // rec: 32 KB
    struct { unsigned short Ash[128][40]; unsigned short Bsh[128][40]; } g;  // 20 KB
  };
};

// ---------------------------------------------------------------- gemm_x body
// Zx2[cg][row][n] = x_row . Wx[:,col] + bg[col]; col = gate*512+cg*8+jj, n = gate*8+jj.
DEVI void gemm_x_tile(SMem& sm, const float* __restrict__ X,
                      const unsigned short* __restrict__ WxT,
                      const float* __restrict__ bg,
                      float* __restrict__ Zx2, int row0, int col0, int tid)
{
  const int lane = tid & 63, wave = tid >> 6;
  const int wr = wave >> 1, wc = wave & 1;
  const int m16 = lane & 15, kg = (lane >> 4) * 8;

  f32x4 acc[4][4] = {};

  for (int k0 = 0; k0 < 512; k0 += 32) {
    __syncthreads();
    #pragma unroll
    for (int i = 0; i < 4; ++i) {
      int idx = i * 256 + tid;
      int r = idx >> 3, kq = idx & 7;
      float4 v = *(const float4*)&X[(size_t)(row0 + r) * 512 + k0 + kq * 4];
      unsigned short* dst = &sm.g.Ash[r][kq * 4];
      dst[0] = f2bf(v.x); dst[1] = f2bf(v.y); dst[2] = f2bf(v.z); dst[3] = f2bf(v.w);
    }
    #pragma unroll
    for (int i = 0; i < 2; ++i) {
      int idx = i * 256 + tid;
      int c = idx >> 2, kq = idx & 3;
      *(uint4*)&sm.g.Bsh[c][kq * 8] =
          *(const uint4*)&WxT[(size_t)(col0 + c) * 512 + k0 + kq * 8];
    }
    __syncthreads();
    bf16x8 fa[4], fb[4];
    #pragma unroll
    for (int mi = 0; mi < 4; ++mi) fa[mi] = *(const bf16x8*)&sm.g.Ash[wr*64 + mi*16 + m16][kg];
    #pragma unroll
    for (int ni = 0; ni < 4; ++ni) fb[ni] = *(const bf16x8*)&sm.g.Bsh[wc*64 + ni*16 + m16][kg];
    #pragma unroll
    for (int mi = 0; mi < 4; ++mi)
      #pragma unroll
      for (int ni = 0; ni < 4; ++ni)
        acc[mi][ni] = __builtin_amdgcn_mfma_f32_16x16x32_bf16(fa[mi], fb[ni], acc[mi][ni], 0, 0, 0);
  }
  const int rg = (lane >> 4) * 4;
  #pragma unroll
  for (int ni = 0; ni < 4; ++ni) {
    int col = col0 + wc*64 + ni*16 + m16;
    float bb = bg[col];
    int gate = col >> 9, hcol = col & 511;
    int cg = hcol >> 3, n = gate * 8 + (hcol & 7);
    #pragma unroll
    for (int mi = 0; mi < 4; ++mi)
      #pragma unroll
      for (int r = 0; r < 4; ++r) {
        int row = row0 + wr*64 + mi*16 + rg + r;
        Zx2[((size_t)cg * 2048 + row) * 32 + n] = acc[mi][ni][r] + bb;
      }
  }
}

// ---------------------------------------------------------------- gemm_x (standalone, chunk 0)
__global__ __launch_bounds__(256) void gemm_x_kernel(
    const float* __restrict__ X, const unsigned short* __restrict__ WxT,
    const float* __restrict__ bg, float* __restrict__ Zx2)
{
  __shared__ SMem sm;
  gemm_x_tile(sm, X, WxT, bg, Zx2, blockIdx.x * 128, blockIdx.y * 128, threadIdx.x);
}

// ---------------------------------------------------------------- fused: rec (blk 0..63) + next-chunk gemm_x (blk 64..255)
__global__ __launch_bounds__(256, 1) void lstm_fused_kernel(
    const unsigned short* __restrict__ WhB,  // [64][32][512] bf16 swizzled
    const float* __restrict__ Zxcur,         // [64][2048][32] this chunk
    unsigned short* __restrict__ hsx,        // [513][64][512] bf16 history
    float* __restrict__ cbuf,                // [64][512] fp32
    int step0,
    unsigned int* __restrict__ cnt,          // [kL+1] per-step wave counters
    float* __restrict__ dout,
    const float* __restrict__ Xnext,         // next chunk x (null on last)
    const unsigned short* __restrict__ WxT,
    const float* __restrict__ bg,
    float* __restrict__ Zxnext)              // next chunk Zx buffer
{
  __shared__ SMem sm;
  const int tid = threadIdx.x;

  if (blockIdx.x >= 64) {
    // ---------------- gemm role: compute Zx for chunk c+1 ----------------
    if (Xnext == nullptr) return;
    for (int tile = (int)blockIdx.x - 64; tile < 256; tile += 192) {
      gemm_x_tile(sm, Xnext, WxT, bg, Zxnext, (tile >> 4) * 128, (tile & 15) * 128, tid);
      __syncthreads();
    }
    return;
  }

  // ---------------- rec role ----------------
  const int cg = blockIdx.x;
  const int j0 = cg * 8;
  const int w   = tid >> 6;           // wave 0..3 -> batch rows w*16..+16
  const int l   = tid & 63;
  const int q   = l & 15;             // n-col within frag
  const int lg  = l >> 4;             // k-group
  const int jj  = q & 7;
  const int i0  = (q < 8) ? 0 : 2;    // acc rows this lane finishes

  // one-time: W slice -> LDS (linear copy; swizzle pre-applied by prep)
  {
    const uint4* wsrc = (const uint4*)(WhB + (size_t)cg * 32 * 512);
    uint4* wdst = (uint4*)sm.WT;
    #pragma unroll
    for (int i = 0; i < 8; ++i) wdst[i * 256 + tid] = wsrc[i * 256 + tid];
  }
  const size_t cidx = (size_t)(w * 16 + lg * 4 + i0) * 512 + j0 + jj;
  float c0r = cbuf[cidx];
  float c1r = cbuf[cidx + 512];
  __syncthreads();   // only barrier in rec role: W-in-LDS visible to all waves

  // Zx for t=0
  float zc0[4], zc1[4];
  {
    const float* zb = Zxcur + ((size_t)cg * 2048 + (w * 16 + lg * 4)) * 32 + q;
    #pragma unroll
    for (int i = 0; i < 4; ++i) { zc0[i] = zb[i * 32]; zc1[i] = zb[i * 32 + 16]; }
  }

  for (int t = 0; t < kT; ++t) {
    const int st = step0 + t;

    // -------- gate: ONE lane per wave polls the single per-step counter.
    // cnt[st]==256 <=> all 256 producer waves drained their hsx[st] stores.
    // (skip t=0: previous dispatch fully drained at the boundary)
    if (t > 0) {
      for (;;) {
        unsigned v = 0u;
        if (l == 0)
          v = __hip_atomic_load(&cnt[st], __ATOMIC_RELAXED,
                                __HIP_MEMORY_SCOPE_AGENT);
        v = (unsigned)__shfl((int)v, 0, 64);
        if (v >= 256u) break;
      }
      asm volatile("" ::: "memory");   // keep A-loads below the gate
    }

    // A-frags direct from global: lane: row w*16+q, k = 32s + lg*8 ..+8
    const unsigned short* hrow =
        hsx + (size_t)st * (kN * kDH) + (w * 16 + q) * 512 + lg * 8;
    bf16x8 A[16];
    #pragma unroll
    for (int s = 0; s < 16; ++s) A[s] = *(const bf16x8*)(hrow + 32 * s);

    // Zx prefetch for t+1 issued BEFORE MFMA: completes under compute, so the
    // vmcnt(0) drain below only pays the h-store round trip.
    float zn0[4], zn1[4];
    if (t + 1 < kT) {
      const float* zb = Zxcur +
          ((size_t)cg * 2048 + ((t + 1) * 64 + w * 16 + lg * 4)) * 32 + q;
      #pragma unroll
      for (int i = 0; i < 4; ++i) { zn0[i] = zb[i * 32]; zn1[i] = zb[i * 32 + 16]; }
    }

    // MFMA: 16 ksteps x 2 n-frags
    f32x4 acc0 = {}, acc1 = {};
    #pragma unroll
    for (int s = 0; s < 16; ++s) {
      const int kb = 4 * s + lg;
      bf16x8 b0 = *(const bf16x8*)&sm.WT[(size_t)q * 512 + ((kb ^ jj) << 3)];
      bf16x8 b1 = *(const bf16x8*)&sm.WT[(size_t)(16 + q) * 512 + ((kb ^ jj) << 3)];
      acc0 = __builtin_amdgcn_mfma_f32_16x16x32_bf16(A[s], b0, acc0, 0, 0, 0);
      acc1 = __builtin_amdgcn_mfma_f32_16x16x32_bf16(A[s], b1, acc1, 0, 0, 0);
    }

    // z = acc + Zx (own cols), then exchange with lane^8 to gather 4 gates
    float t0[4], t1[4], ot0[4], ot1[4];
    #pragma unroll
    for (int i = 0; i < 4; ++i) { t0[i] = acc0[i] + zc0[i]; t1[i] = acc1[i] + zc1[i]; }
    #pragma unroll
    for (int i = 0; i < 4; ++i) {
      ot0[i] = __shfl_xor(t0[i], 8, 64);
      ot1[i] = __shfl_xor(t1[i], 8, 64);
    }
    float hh[2];
    #pragma unroll
    for (int u = 0; u < 2; ++u) {
      const int i = i0 + u;
      float zf = (q < 8) ? t0[i] : ot0[i];
      float zc = (q < 8) ? ot0[i] : t0[i];
      float zi = (q < 8) ? t1[i] : ot1[i];
      float zo = (q < 8) ? ot1[i] : t1[i];
      float fg = sigm(zf), ig = sigm(zi), og = sigm(zo);
      float Ct = tanh_f(zc);
      float& cr = u ? c1r : c0r;
      cr = fg * cr + ig * Ct;
      hh[u] = og * tanh_f(cr);
    }

    // store h (bf16 pairs packed per dword, agent-scope write-through)
    {
      unsigned short hb0 = f2bf(hh[0]), hb1 = f2bf(hh[1]);
      unsigned o0 = (unsigned)(unsigned short)__shfl_xor((int)hb0, 1, 64);
      unsigned o1 = (unsigned)(unsigned short)__shfl_xor((int)hb1, 1, 64);
      if ((q & 1) == 0) {
        const size_t base = (size_t)(st + 1) * (kN * kDH) +
                            (size_t)(w * 16 + lg * 4 + i0) * 512 + j0 + jj;
        __hip_atomic_store((unsigned*)&hsx[base], ((unsigned)hb0) | (o0 << 16),
                           __ATOMIC_RELAXED, __HIP_MEMORY_SCOPE_AGENT);
        __hip_atomic_store((unsigned*)&hsx[base + 512], ((unsigned)hb1) | (o1 << 16),
                           __ATOMIC_RELAXED, __HIP_MEMORY_SCOPE_AGENT);
      }
      if (st == kL - 1) {
        dout[kOutSz + cidx] = hh[0];
        dout[kOutSz + cidx + 512] = hh[1];
        dout[kOutSz + (size_t)kN * kDH + cidx] = c0r;
        dout[kOutSz + (size_t)kN * kDH + cidx + 512] = c1r;
      }
    }

    // drain THIS wave's h stores (per-wave vmcnt), then publish: one
    // fire-and-forget add per wave on the per-step aggregate counter.
    // No barriers in the step loop.
    asm volatile("s_waitcnt vmcnt(0)" ::: "memory");
    if (l == 0)
      __hip_atomic_fetch_add(&cnt[st + 1], 1u, __ATOMIC_RELAXED,
                             __HIP_MEMORY_SCOPE_AGENT);

    if (t + 1 < kT) {
      #pragma unroll
      for (int i = 0; i < 4; ++i) { zc0[i] = zn0[i]; zc1[i] = zn1[i]; }
    }
  }

  cbuf[cidx] = c0r;
  cbuf[cidx + 512] = c1r;
}

// ---------------------------------------------------------------- gemm_out
__global__ __launch_bounds__(256) void gemm_out_kernel(
    const unsigned short* __restrict__ Hs,   // [32768][512] bf16 (h_1..h_512)
    const unsigned short* __restrict__ WoT,  // [512][512] bf16 (B^T)
    const float* __restrict__ bout,
    float* __restrict__ out)                 // [32768][512] fp32
{
  __shared__ unsigned short Ash[128][40];
  __shared__ unsigned short Bsh[128][40];
  const int row0 = blockIdx.x * 128, col0 = blockIdx.y * 128;
  const int tid = threadIdx.x;
  const int lane = tid & 63, wave = tid >> 6;
  const int wr = wave >> 1, wc = wave & 1;
  const int m16 = lane & 15, kg = (lane >> 4) * 8;

  f32x4 acc[4][4] = {};

  for (int k0 = 0; k0 < 512; k0 += 32) {
    __syncthreads();
    #pragma unroll
    for (int i = 0; i < 2; ++i) {
      int idx = i * 256 + tid;
      int r = idx >> 2, kq = idx & 3;
      *(uint4*)&Ash[r][kq * 8] =
          *(const uint4*)&Hs[(size_t)(row0 + r) * 512 + k0 + kq * 8];
    }
    #pragma unroll
    for (int i = 0; i < 2; ++i) {
      int idx = i * 256 + tid;
      int c = idx >> 2, kq = idx & 3;
      *(uint4*)&Bsh[c][kq * 8] =
          *(const uint4*)&WoT[(size_t)(col0 + c) * 512 + k0 + kq * 8];
    }
    __syncthreads();
    bf16x8 fa[4], fb[4];
    #pragma unroll
    for (int mi = 0; mi < 4; ++mi) fa[mi] = *(const bf16x8*)&Ash[wr*64 + mi*16 + m16][kg];
    #pragma unroll
    for (int ni = 0; ni < 4; ++ni) fb[ni] = *(const bf16x8*)&Bsh[wc*64 + ni*16 + m16][kg];
    #pragma unroll
    for (int mi = 0; mi < 4; ++mi)
      #pragma unroll
      for (int ni = 0; ni < 4; ++ni)
        acc[mi][ni] = __builtin_amdgcn_mfma_f32_16x16x32_bf16(fa[mi], fb[ni], acc[mi][ni], 0, 0, 0);
  }
  const int rg = (lane >> 4) * 4;
  #pragma unroll
  for (int ni = 0; ni < 4; ++ni) {
    int col = col0 + wc*64 + ni*16 + m16;
    float bb = bout[col];
    #pragma unroll
    for (int mi = 0; mi < 4; ++mi)
      #pragma unroll
      for (int r = 0; r < 4; ++r)
        out[(size_t)(row0 + wr*64 + mi*16 + rg + r) * 512 + col] = acc[mi][ni][r] + bb;
  }
}

// ---------------------------------------------------------------- launch
extern "C" void kernel_launch(void* const* d_in, const int* in_sizes, int n_in,
                              void* d_out, int out_size, void* d_ws, size_t ws_size,
                              hipStream_t stream) {
  (void)in_sizes; (void)n_in; (void)out_size; (void)ws_size;
  const float* x    = (const float*)d_in[0];
  const float* h0   = (const float*)d_in[1];
  const float* c0   = (const float*)d_in[2];
  const float* Wf   = (const float*)d_in[3];
  const float* bf_  = (const float*)d_in[4];
  const float* Wc   = (const float*)d_in[5];
  const float* bc_  = (const float*)d_in[6];
  const float* Wi_  = (const float*)d_in[7];
  const float* bi_  = (const float*)d_in[8];
  const float* Wo   = (const float*)d_in[9];
  const float* bo_  = (const float*)d_in[10];
  const float* Wout = (const float*)d_in[11];
  const float* bout = (const float*)d_in[12];
  float* out = (float*)d_out;

  char* ws = (char*)d_ws;
  size_t off = 0;
  auto alloc = [&](size_t bytes) -> void* {
    void* p = ws + off;
    off += (bytes + 255) & ~(size_t)255;
    return p;
  };
  float*          ZxA = (float*)alloc((size_t)kT * kN * kG * 4);                 // 16 MB
  float*          ZxB = (float*)alloc((size_t)kT * kN * kG * 4);                 // 16 MB
  unsigned short* hsx = (unsigned short*)alloc((size_t)(kL + 1) * kN * kDH * 2); // 33.6 MB
  unsigned short* WxT = (unsigned short*)alloc((size_t)kG * 512 * 2);            // 2 MB
  unsigned short* WoT = (unsigned short*)alloc((size_t)512 * 512 * 2);           // 0.5 MB
  unsigned short* WhB = (unsigned short*)alloc((size_t)64 * 32 * 512 * 2);       // 2 MB
  float*          bg  = (float*)alloc((size_t)kG * 4);
  float*          cbf = (float*)alloc((size_t)kN * kDH * 4);
  unsigned int*   cnt = (unsigned int*)alloc((size_t)(kL + 1) * 4);              // 2 KB

  prep_kernel<<<1024, 256, 0, stream>>>(Wf, Wc, Wi_, Wo, bf_, bc_, bi_, bo_,
                                        Wout, h0, c0, WxT, WoT, WhB, bg, hsx, cbf, cnt);
  // chunk 0's Zx
  gemm_x_kernel<<<dim3(16, 16), 256, 0, stream>>>(x, WxT, bg, ZxA);
  for (int c = 0; c < kChunks; ++c) {
    float* Zxcur = (c & 1) ? ZxB : ZxA;
    float* Zxnxt = (c & 1) ? ZxA : ZxB;
    const float* xnext = (c + 1 < kChunks)
        ? x + (size_t)(c + 1) * kT * kN * kDIN : nullptr;
    lstm_fused_kernel<<<256, 256, 0, stream>>>(
        WhB, Zxcur, hsx, cbf, c * kT, cnt, out, xnext, WxT, bg, Zxnxt);
  }
  gemm_out_kernel<<<dim3(256, 4), 256, 0, stream>>>(
      hsx + (size_t)kN * kDH, WoT, bout, out);
}

// Round 7
// 2558.638 us; speedup vs baseline: 16.7106x; 1.3915x over previous
//
#include <hip/hip_runtime.h>

typedef float  f32x4  __attribute__((ext_vector_type(4)));
typedef short  bf16x8 __attribute__((ext_vector_type(8)));

#define DEVI static __device__ __forceinline__

namespace {
constexpr int kL   = 512;
constexpr int kN   = 64;
constexpr int kDH  = 512;
constexpr int kDIN = 512;
constexpr int kG   = 2048;            // 4*kDH
constexpr int kT   = 32;              // timesteps per chunk
constexpr int kChunks = kL / kT;      // 16
constexpr int kHS  = kN * kDH;        // 32768 elements per step slice
constexpr size_t kOutSz = (size_t)kL * kN * kDIN;  // 16,777,216 floats
}

// hsx layout (bf16): [t][chunk=c/8][w=n/16][n%16][c%8]
//   OFF(t,n,c) = t*32768 + (c>>3)*512 + ((n>>4)&3)*128 + (n&15)*8 + (c&7)
// => each producer wave's step output (16 rows x 8 cols) is ONE contiguous
//    256 B block: full-line IC writes, no partial-line RMW.

DEVI unsigned short f2bf(float f) {
  union { float f; unsigned u; } v; v.f = f;
  unsigned r = v.u + 0x7FFFu + ((v.u >> 16) & 1u);   // RNE
  return (unsigned short)(r >> 16);
}
DEVI float sigm(float z) { return 1.f / (1.f + __expf(-z)); }
DEVI float tanh_f(float z) { return 2.f / (1.f + __expf(-2.f * z)) - 1.f; }

// ---------------------------------------------------------------- prep
__global__ void prep_kernel(
    const float* __restrict__ Wf, const float* __restrict__ Wc,
    const float* __restrict__ Wi, const float* __restrict__ Wo,
    const float* __restrict__ bf, const float* __restrict__ bc,
    const float* __restrict__ bi, const float* __restrict__ bo,
    const float* __restrict__ Wout,
    const float* __restrict__ h0, const float* __restrict__ c0,
    unsigned short* __restrict__ WxT, unsigned short* __restrict__ WoT,
    unsigned short* __restrict__ WhB, float* __restrict__ bg,
    unsigned short* __restrict__ hsx, float* __restrict__ cbuf,
    unsigned int* __restrict__ flags)
{
  const int gid = blockIdx.x * blockDim.x + threadIdx.x;
  const int stride = gridDim.x * blockDim.x;
  const float* Wg[4]  = {Wf, Wc, Wi, Wo};
  const float* bgs[4] = {bf, bc, bi, bo};

  for (int i = gid; i < 64; i += stride) flags[i] = 0u;

  for (int i = gid; i < kG * 512; i += stride) {
    int k = i >> 11, g = i & 2047;
    WxT[(size_t)g * 512 + k] = f2bf(Wg[g >> 9][(size_t)k * 512 + (g & 511)]);
  }
  for (int i = gid; i < 512 * 512; i += stride) {
    int k = i >> 9, c = i & 511;
    WoT[(size_t)c * 512 + k] = f2bf(Wout[(size_t)k * 512 + c]);
  }
  // WhB: i = k*1024 + gate*512 + hcol  -> coalesced source reads
  for (int i = gid; i < 4 * 512 * 512; i += stride) {
    int hcol = i & 511;
    int gate = (i >> 9) & 3;
    int k    = i >> 11;
    int cg = hcol >> 3, jj = hcol & 7;
    int n  = gate * 8 + jj;
    int kblk = k >> 3, kin = k & 7;
    size_t dst = ((size_t)cg * 32 + n) * 512 + (((kblk ^ (n & 7)) << 3) | kin);
    WhB[dst] = f2bf(Wg[gate][(size_t)(512 + k) * 512 + hcol]);
  }
  for (int i = gid; i < kG; i += stride) bg[i] = bgs[i >> 9][i & 511];
  for (int i = gid; i < kN * kDH; i += stride) {
    int n = i >> 9, c = i & 511;   // h0[n][c]
    hsx[((size_t)(c >> 3)) * 512 + ((n >> 4) * 128) + ((n & 15) * 8) + (c & 7)]
        = f2bf(h0[i]);             // hsx[0] in chunked layout
    cbuf[i] = c0[i];
  }
}

// Shared-memory overlay for the fused kernel's two roles.
struct SMem {
  union {
    unsigned short WT[32 * 512];                                   // rec: 32 KB
    struct { unsigned short Ash[128][40]; unsigned short Bsh[128][40]; } g;  // 20 KB
  };
};

// ---------------------------------------------------------------- gemm_x body
// Zx2[cg][row][n] = x_row . Wx[:,col] + bg[col]; col = gate*512+cg*8+jj, n = gate*8+jj.
DEVI void gemm_x_tile(SMem& sm, const float* __restrict__ X,
                      const unsigned short* __restrict__ WxT,
                      const float* __restrict__ bg,
                      float* __restrict__ Zx2, int row0, int col0, int tid)
{
  const int lane = tid & 63, wave = tid >> 6;
  const int wr = wave >> 1, wc = wave & 1;
  const int m16 = lane & 15, kg = (lane >> 4) * 8;

  f32x4 acc[4][4] = {};

  for (int k0 = 0; k0 < 512; k0 += 32) {
    __syncthreads();
    #pragma unroll
    for (int i = 0; i < 4; ++i) {
      int idx = i * 256 + tid;
      int r = idx >> 3, kq = idx & 7;
      float4 v = *(const float4*)&X[(size_t)(row0 + r) * 512 + k0 + kq * 4];
      unsigned short* dst = &sm.g.Ash[r][kq * 4];
      dst[0] = f2bf(v.x); dst[1] = f2bf(v.y); dst[2] = f2bf(v.z); dst[3] = f2bf(v.w);
    }
    #pragma unroll
    for (int i = 0; i < 2; ++i) {
      int idx = i * 256 + tid;
      int c = idx >> 2, kq = idx & 3;
      *(uint4*)&sm.g.Bsh[c][kq * 8] =
          *(const uint4*)&WxT[(size_t)(col0 + c) * 512 + k0 + kq * 8];
    }
    __syncthreads();
    bf16x8 fa[4], fb[4];
    #pragma unroll
    for (int mi = 0; mi < 4; ++mi) fa[mi] = *(const bf16x8*)&sm.g.Ash[wr*64 + mi*16 + m16][kg];
    #pragma unroll
    for (int ni = 0; ni < 4; ++ni) fb[ni] = *(const bf16x8*)&sm.g.Bsh[wc*64 + ni*16 + m16][kg];
    #pragma unroll
    for (int mi = 0; mi < 4; ++mi)
      #pragma unroll
      for (int ni = 0; ni < 4; ++ni)
        acc[mi][ni] = __builtin_amdgcn_mfma_f32_16x16x32_bf16(fa[mi], fb[ni], acc[mi][ni], 0, 0, 0);
  }
  const int rg = (lane >> 4) * 4;
  #pragma unroll
  for (int ni = 0; ni < 4; ++ni) {
    int col = col0 + wc*64 + ni*16 + m16;
    float bb = bg[col];
    int gate = col >> 9, hcol = col & 511;
    int cg = hcol >> 3, n = gate * 8 + (hcol & 7);
    #pragma unroll
    for (int mi = 0; mi < 4; ++mi)
      #pragma unroll
      for (int r = 0; r < 4; ++r) {
        int row = row0 + wr*64 + mi*16 + rg + r;
        Zx2[((size_t)cg * 2048 + row) * 32 + n] = acc[mi][ni][r] + bb;
      }
  }
}

// ---------------------------------------------------------------- gemm_x (standalone, chunk 0)
__global__ __launch_bounds__(256) void gemm_x_kernel(
    const float* __restrict__ X, const unsigned short* __restrict__ WxT,
    const float* __restrict__ bg, float* __restrict__ Zx2)
{
  __shared__ SMem sm;
  gemm_x_tile(sm, X, WxT, bg, Zx2, blockIdx.x * 128, blockIdx.y * 128, threadIdx.x);
}

// ---------------------------------------------------------------- fused: rec (blk 0..63) + next-chunk gemm_x (blk 64..255)
__global__ __launch_bounds__(256, 1) void lstm_fused_kernel(
    const unsigned short* __restrict__ WhB,  // [64][32][512] bf16 swizzled
    const float* __restrict__ Zxcur,         // [64][2048][32] this chunk
    unsigned short* __restrict__ hsx,        // [513][...] bf16, chunked layout
    float* __restrict__ cbuf,                // [64][512] fp32
    int step0,
    unsigned int* __restrict__ flags,        // [64]
    float* __restrict__ dout,
    const float* __restrict__ Xnext,         // next chunk x (null on last)
    const unsigned short* __restrict__ WxT,
    const float* __restrict__ bg,
    float* __restrict__ Zxnext)              // next chunk Zx buffer
{
  __shared__ SMem sm;
  const int tid = threadIdx.x;

  if (blockIdx.x >= 64) {
    // ---------------- gemm role: compute Zx for chunk c+1 ----------------
    if (Xnext == nullptr) return;
    for (int tile = (int)blockIdx.x - 64; tile < 256; tile += 192) {
      gemm_x_tile(sm, Xnext, WxT, bg, Zxnext, (tile >> 4) * 128, (tile & 15) * 128, tid);
      __syncthreads();
    }
    return;
  }

  // ---------------- rec role ----------------
  const int cg = blockIdx.x;
  const int j0 = cg * 8;
  const int w   = tid >> 6;           // wave 0..3 -> batch rows w*16..+16
  const int l   = tid & 63;
  const int q   = l & 15;             // n-col within frag
  const int lg  = l >> 4;             // k-group
  const int jj  = q & 7;
  const int i0  = (q < 8) ? 0 : 2;    // acc rows this lane finishes

  // one-time: W slice -> LDS (linear copy; swizzle pre-applied by prep)
  {
    const uint4* wsrc = (const uint4*)(WhB + (size_t)cg * 32 * 512);
    uint4* wdst = (uint4*)sm.WT;
    #pragma unroll
    for (int i = 0; i < 8; ++i) wdst[i * 256 + tid] = wsrc[i * 256 + tid];
  }
  const size_t cidx = (size_t)(w * 16 + lg * 4 + i0) * 512 + j0 + jj;
  float c0r = cbuf[cidx];
  float c1r = cbuf[cidx + 512];
  __syncthreads();

  // Zx for t=0
  float zc0[4], zc1[4];
  {
    const float* zb = Zxcur + ((size_t)cg * 2048 + (w * 16 + lg * 4)) * 32 + q;
    #pragma unroll
    for (int i = 0; i < 4; ++i) { zc0[i] = zb[i * 32]; zc1[i] = zb[i * 32 + 16]; }
  }

  for (int t = 0; t < kT; ++t) {
    const int st = step0 + t;

    // wait for hsx[st] (skip t=0: previous dispatch completed it).
    // Wave 0 polls (coalesced 64-flag load, no stores!), others wait at barrier.
    if (t > 0) {
      if (tid < 64) {
        for (;;) {
          int fv = (int)__hip_atomic_load(&flags[l], __ATOMIC_RELAXED,
                                          __HIP_MEMORY_SCOPE_AGENT);
          if (__all(fv >= st)) break;
        }
      }
      __syncthreads();
    }

    // A-frags from chunked layout: A[s] = row w*16+q, cols 8*(4s+lg)..+7
    //   addr = st*32768 + (4s+lg)*512 + w*128 + q*8  (16B per load, coalesced
    //   256B per 16-lane group)
    const unsigned short* hrow =
        hsx + (size_t)st * kHS + (size_t)lg * 512 + w * 128 + q * 8;
    bf16x8 A[16];
    #pragma unroll
    for (int s = 0; s < 16; ++s) A[s] = *(const bf16x8*)(hrow + 2048 * s);

    // Zx prefetch for t+1 issued BEFORE MFMA: completes under compute, so the
    // vmcnt(0) drain below only pays the h-store round trip.
    float zn0[4], zn1[4];
    if (t + 1 < kT) {
      const float* zb = Zxcur +
          ((size_t)cg * 2048 + ((t + 1) * 64 + w * 16 + lg * 4)) * 32 + q;
      #pragma unroll
      for (int i = 0; i < 4; ++i) { zn0[i] = zb[i * 32]; zn1[i] = zb[i * 32 + 16]; }
    }

    // MFMA: 16 ksteps x 2 n-frags
    f32x4 acc0 = {}, acc1 = {};
    #pragma unroll
    for (int s = 0; s < 16; ++s) {
      const int kb = 4 * s + lg;
      bf16x8 b0 = *(const bf16x8*)&sm.WT[(size_t)q * 512 + ((kb ^ jj) << 3)];
      bf16x8 b1 = *(const bf16x8*)&sm.WT[(size_t)(16 + q) * 512 + ((kb ^ jj) << 3)];
      acc0 = __builtin_amdgcn_mfma_f32_16x16x32_bf16(A[s], b0, acc0, 0, 0, 0);
      acc1 = __builtin_amdgcn_mfma_f32_16x16x32_bf16(A[s], b1, acc1, 0, 0, 0);
    }

    // z = acc + Zx (own cols), then exchange with lane^8 to gather 4 gates
    float t0[4], t1[4], ot0[4], ot1[4];
    #pragma unroll
    for (int i = 0; i < 4; ++i) { t0[i] = acc0[i] + zc0[i]; t1[i] = acc1[i] + zc1[i]; }
    #pragma unroll
    for (int i = 0; i < 4; ++i) {
      ot0[i] = __shfl_xor(t0[i], 8, 64);
      ot1[i] = __shfl_xor(t1[i], 8, 64);
    }
    float hh[2];
    #pragma unroll
    for (int u = 0; u < 2; ++u) {
      const int i = i0 + u;
      float zf = (q < 8) ? t0[i] : ot0[i];
      float zc = (q < 8) ? ot0[i] : t0[i];
      float zi = (q < 8) ? t1[i] : ot1[i];
      float zo = (q < 8) ? ot1[i] : t1[i];
      float fg = sigm(zf), ig = sigm(zi), og = sigm(zo);
      float Ct = tanh_f(zc);
      float& cr = u ? c1r : c0r;
      cr = fg * cr + ig * Ct;
      hh[u] = og * tanh_f(cr);
    }

    // store h: wave's 16x8 tile is ONE contiguous 256 B block in the chunked
    // layout -> full-line IC writes, no partial-line RMW, fast vmcnt drain.
    {
      unsigned short hb0 = f2bf(hh[0]), hb1 = f2bf(hh[1]);
      unsigned o0 = (unsigned)(unsigned short)__shfl_xor((int)hb0, 1, 64);
      unsigned o1 = (unsigned)(unsigned short)__shfl_xor((int)hb1, 1, 64);
      if ((q & 1) == 0) {
        const size_t base = (size_t)(st + 1) * kHS + (size_t)cg * 512 +
                            w * 128 + (lg * 4 + i0) * 8 + jj;
        __hip_atomic_store((unsigned*)&hsx[base], ((unsigned)hb0) | (o0 << 16),
                           __ATOMIC_RELAXED, __HIP_MEMORY_SCOPE_AGENT);
        __hip_atomic_store((unsigned*)&hsx[base + 8], ((unsigned)hb1) | (o1 << 16),
                           __ATOMIC_RELAXED, __HIP_MEMORY_SCOPE_AGENT);
      }
      if (st == kL - 1) {
        dout[kOutSz + cidx] = hh[0];
        dout[kOutSz + cidx + 512] = hh[1];
        dout[kOutSz + (size_t)kN * kDH + cidx] = c0r;
        dout[kOutSz + (size_t)kN * kDH + cidx + 512] = c1r;
      }
    }

    // drain h stores, then publish flag
    asm volatile("s_waitcnt vmcnt(0)" ::: "memory");
    __syncthreads();
    if (tid == 0)
      __hip_atomic_store(&flags[cg], (unsigned)(st + 1), __ATOMIC_RELAXED,
                         __HIP_MEMORY_SCOPE_AGENT);

    if (t + 1 < kT) {
      #pragma unroll
      for (int i = 0; i < 4; ++i) { zc0[i] = zn0[i]; zc1[i] = zn1[i]; }
    }
  }

  cbuf[cidx] = c0r;
  cbuf[cidx + 512] = c1r;
}

// ---------------------------------------------------------------- gemm_out
__global__ __launch_bounds__(256) void gemm_out_kernel(
    const unsigned short* __restrict__ Hs,   // hsx + 32768: h_1.. in chunked layout
    const unsigned short* __restrict__ WoT,  // [512][512] bf16 (B^T)
    const float* __restrict__ bout,
    float* __restrict__ out)                 // [32768][512] fp32
{
  __shared__ unsigned short Ash[128][40];
  __shared__ unsigned short Bsh[128][40];
  const int row0 = blockIdx.x * 128, col0 = blockIdx.y * 128;
  const int tid = threadIdx.x;
  const int lane = tid & 63, wave = tid >> 6;
  const int wr = wave >> 1, wc = wave & 1;
  const int m16 = lane & 15, kg = (lane >> 4) * 8;

  f32x4 acc[4][4] = {};

  for (int k0 = 0; k0 < 512; k0 += 32) {
    __syncthreads();
    #pragma unroll
    for (int i = 0; i < 2; ++i) {
      int idx = i * 256 + tid;
      int r = idx >> 2, kq = idx & 3;
      int grow = row0 + r;               // h row: t*64 + n  (t = step-1)
      size_t src = (size_t)(grow >> 6) * kHS + (size_t)((k0 >> 3) + kq) * 512 +
                   ((grow >> 4) & 3) * 128 + (grow & 15) * 8;
      *(uint4*)&Ash[r][kq * 8] = *(const uint4*)&Hs[src];
    }
    #pragma unroll
    for (int i = 0; i < 2; ++i) {
      int idx = i * 256 + tid;
      int c = idx >> 2, kq = idx & 3;
      *(uint4*)&Bsh[c][kq * 8] =
          *(const uint4*)&WoT[(size_t)(col0 + c) * 512 + k0 + kq * 8];
    }
    __syncthreads();
    bf16x8 fa[4], fb[4];
    #pragma unroll
    for (int mi = 0; mi < 4; ++mi) fa[mi] = *(const bf16x8*)&Ash[wr*64 + mi*16 + m16][kg];
    #pragma unroll
    for (int ni = 0; ni < 4; ++ni) fb[ni] = *(const bf16x8*)&Bsh[wc*64 + ni*16 + m16][kg];
    #pragma unroll
    for (int mi = 0; mi < 4; ++mi)
      #pragma unroll
      for (int ni = 0; ni < 4; ++ni)
        acc[mi][ni] = __builtin_amdgcn_mfma_f32_16x16x32_bf16(fa[mi], fb[ni], acc[mi][ni], 0, 0, 0);
  }
  const int rg = (lane >> 4) * 4;
  #pragma unroll
  for (int ni = 0; ni < 4; ++ni) {
    int col = col0 + wc*64 + ni*16 + m16;
    float bb = bout[col];
    #pragma unroll
    for (int mi = 0; mi < 4; ++mi)
      #pragma unroll
      for (int r = 0; r < 4; ++r)
        out[(size_t)(row0 + wr*64 + mi*16 + rg + r) * 512 + col] = acc[mi][ni][r] + bb;
  }
}

// ---------------------------------------------------------------- launch
extern "C" void kernel_launch(void* const* d_in, const int* in_sizes, int n_in,
                              void* d_out, int out_size, void* d_ws, size_t ws_size,
                              hipStream_t stream) {
  (void)in_sizes; (void)n_in; (void)out_size; (void)ws_size;
  const float* x    = (const float*)d_in[0];
  const float* h0   = (const float*)d_in[1];
  const float* c0   = (const float*)d_in[2];
  const float* Wf   = (const float*)d_in[3];
  const float* bf_  = (const float*)d_in[4];
  const float* Wc   = (const float*)d_in[5];
  const float* bc_  = (const float*)d_in[6];
  const float* Wi_  = (const float*)d_in[7];
  const float* bi_  = (const float*)d_in[8];
  const float* Wo   = (const float*)d_in[9];
  const float* bo_  = (const float*)d_in[10];
  const float* Wout = (const float*)d_in[11];
  const float* bout = (const float*)d_in[12];
  float* out = (float*)d_out;

  char* ws = (char*)d_ws;
  size_t off = 0;
  auto alloc = [&](size_t bytes) -> void* {
    void* p = ws + off;
    off += (bytes + 255) & ~(size_t)255;
    return p;
  };
  float*          ZxA = (float*)alloc((size_t)kT * kN * kG * 4);                 // 16 MB
  float*          ZxB = (float*)alloc((size_t)kT * kN * kG * 4);                 // 16 MB
  unsigned short* hsx = (unsigned short*)alloc((size_t)(kL + 1) * kN * kDH * 2); // 33.6 MB
  unsigned short* WxT = (unsigned short*)alloc((size_t)kG * 512 * 2);            // 2 MB
  unsigned short* WoT = (unsigned short*)alloc((size_t)512 * 512 * 2);           // 0.5 MB
  unsigned short* WhB = (unsigned short*)alloc((size_t)64 * 32 * 512 * 2);       // 2 MB
  float*          bg  = (float*)alloc((size_t)kG * 4);
  float*          cbf = (float*)alloc((size_t)kN * kDH * 4);
  unsigned int*   flg = (unsigned int*)alloc(256);

  prep_kernel<<<1024, 256, 0, stream>>>(Wf, Wc, Wi_, Wo, bf_, bc_, bi_, bo_,
                                        Wout, h0, c0, WxT, WoT, WhB, bg, hsx, cbf, flg);
  // chunk 0's Zx
  gemm_x_kernel<<<dim3(16, 16), 256, 0, stream>>>(x, WxT, bg, ZxA);
  for (int c = 0; c < kChunks; ++c) {
    float* Zxcur = (c & 1) ? ZxB : ZxA;
    float* Zxnxt = (c & 1) ? ZxA : ZxB;
    const float* xnext = (c + 1 < kChunks)
        ? x + (size_t)(c + 1) * kT * kN * kDIN : nullptr;
    lstm_fused_kernel<<<256, 256, 0, stream>>>(
        WhB, Zxcur, hsx, cbf, c * kT, flg, out, xnext, WxT, bg, Zxnxt);
  }
  gemm_out_kernel<<<dim3(256, 4), 256, 0, stream>>>(
      hsx + (size_t)kN * kDH, WoT, bout, out);
}

// Round 8
// 1836.148 us; speedup vs baseline: 23.2859x; 1.3935x over previous
//
#include <hip/hip_runtime.h>

typedef float  f32x4  __attribute__((ext_vector_type(4)));
typedef short  bf16x8 __attribute__((ext_vector_type(8)));

#define DEVI static __device__ __forceinline__

namespace {
constexpr int kL   = 512;
constexpr int kN   = 64;
constexpr int kDH  = 512;
constexpr int kDIN = 512;
constexpr int kG   = 2048;            // 4*kDH
constexpr int kT   = 32;              // timesteps per chunk
constexpr int kChunks = kL / kT;      // 16
constexpr int kHS  = kN * kDH;        // 32768 elements per step slice
constexpr int kFP = 16;               // flag padding: 1 flag per 64B line
constexpr size_t kOutSz = (size_t)kL * kN * kDIN;  // 16,777,216 floats
}

// hsx layout (bf16): [t][chunk=c/8][w=n/16][n%16][c%8]
//   OFF(t,n,c) = t*32768 + (c>>3)*512 + ((n>>4)&3)*128 + (n&15)*8 + (c&7)
// => each producer wave's step output (16 rows x 8 cols) is ONE contiguous
//    256 B block: full-line IC writes, fast vmcnt drain (R7 win).
// flags: ONE per 64B line (flags[cg*16]) so the 64-wave poll storm spreads
// across 64 TCC lines instead of serializing on 2 hot lines (R8 variable).

DEVI unsigned short f2bf(float f) {
  union { float f; unsigned u; } v; v.f = f;
  unsigned r = v.u + 0x7FFFu + ((v.u >> 16) & 1u);   // RNE
  return (unsigned short)(r >> 16);
}
DEVI float sigm(float z) { return 1.f / (1.f + __expf(-z)); }
DEVI float tanh_f(float z) { return 2.f / (1.f + __expf(-2.f * z)) - 1.f; }

// ---------------------------------------------------------------- prep
__global__ void prep_kernel(
    const float* __restrict__ Wf, const float* __restrict__ Wc,
    const float* __restrict__ Wi, const float* __restrict__ Wo,
    const float* __restrict__ bf, const float* __restrict__ bc,
    const float* __restrict__ bi, const float* __restrict__ bo,
    const float* __restrict__ Wout,
    const float* __restrict__ h0, const float* __restrict__ c0,
    unsigned short* __restrict__ WxT, unsigned short* __restrict__ WoT,
    unsigned short* __restrict__ WhB, float* __restrict__ bg,
    unsigned short* __restrict__ hsx, float* __restrict__ cbuf,
    unsigned int* __restrict__ flags)
{
  const int gid = blockIdx.x * blockDim.x + threadIdx.x;
  const int stride = gridDim.x * blockDim.x;
  const float* Wg[4]  = {Wf, Wc, Wi, Wo};
  const float* bgs[4] = {bf, bc, bi, bo};

  for (int i = gid; i < 64 * kFP; i += stride) flags[i] = 0u;

  for (int i = gid; i < kG * 512; i += stride) {
    int k = i >> 11, g = i & 2047;
    WxT[(size_t)g * 512 + k] = f2bf(Wg[g >> 9][(size_t)k * 512 + (g & 511)]);
  }
  for (int i = gid; i < 512 * 512; i += stride) {
    int k = i >> 9, c = i & 511;
    WoT[(size_t)c * 512 + k] = f2bf(Wout[(size_t)k * 512 + c]);
  }
  // WhB: i = k*1024 + gate*512 + hcol  -> coalesced source reads
  for (int i = gid; i < 4 * 512 * 512; i += stride) {
    int hcol = i & 511;
    int gate = (i >> 9) & 3;
    int k    = i >> 11;
    int cg = hcol >> 3, jj = hcol & 7;
    int n  = gate * 8 + jj;
    int kblk = k >> 3, kin = k & 7;
    size_t dst = ((size_t)cg * 32 + n) * 512 + (((kblk ^ (n & 7)) << 3) | kin);
    WhB[dst] = f2bf(Wg[gate][(size_t)(512 + k) * 512 + hcol]);
  }
  for (int i = gid; i < kG; i += stride) bg[i] = bgs[i >> 9][i & 511];
  for (int i = gid; i < kN * kDH; i += stride) {
    int n = i >> 9, c = i & 511;   // h0[n][c]
    hsx[((size_t)(c >> 3)) * 512 + ((n >> 4) * 128) + ((n & 15) * 8) + (c & 7)]
        = f2bf(h0[i]);             // hsx[0] in chunked layout
    cbuf[i] = c0[i];
  }
}

// Shared-memory overlay for the fused kernel's two roles.
struct SMem {
  union {
    unsigned short WT[32 * 512];                                   // rec: 32 KB
    struct { unsigned short Ash[128][40]; unsigned short Bsh[128][40]; } g;  // 20 KB
  };
};

// ---------------------------------------------------------------- gemm_x body
// Zx2[cg][row][n] = x_row . Wx[:,col] + bg[col]; col = gate*512+cg*8+jj, n = gate*8+jj.
DEVI void gemm_x_tile(SMem& sm, const float* __restrict__ X,
                      const unsigned short* __restrict__ WxT,
                      const float* __restrict__ bg,
                      float* __restrict__ Zx2, int row0, int col0, int tid)
{
  const int lane = tid & 63, wave = tid >> 6;
  const int wr = wave >> 1, wc = wave & 1;
  const int m16 = lane & 15, kg = (lane >> 4) * 8;

  f32x4 acc[4][4] = {};

  for (int k0 = 0; k0 < 512; k0 += 32) {
    __syncthreads();
    #pragma unroll
    for (int i = 0; i < 4; ++i) {
      int idx = i * 256 + tid;
      int r = idx >> 3, kq = idx & 7;
      float4 v = *(const float4*)&X[(size_t)(row0 + r) * 512 + k0 + kq * 4];
      unsigned short* dst = &sm.g.Ash[r][kq * 4];
      dst[0] = f2bf(v.x); dst[1] = f2bf(v.y); dst[2] = f2bf(v.z); dst[3] = f2bf(v.w);
    }
    #pragma unroll
    for (int i = 0; i < 2; ++i) {
      int idx = i * 256 + tid;
      int c = idx >> 2, kq = idx & 3;
      *(uint4*)&sm.g.Bsh[c][kq * 8] =
          *(const uint4*)&WxT[(size_t)(col0 + c) * 512 + k0 + kq * 8];
    }
    __syncthreads();
    bf16x8 fa[4], fb[4];
    #pragma unroll
    for (int mi = 0; mi < 4; ++mi) fa[mi] = *(const bf16x8*)&sm.g.Ash[wr*64 + mi*16 + m16][kg];
    #pragma unroll
    for (int ni = 0; ni < 4; ++ni) fb[ni] = *(const bf16x8*)&sm.g.Bsh[wc*64 + ni*16 + m16][kg];
    #pragma unroll
    for (int mi = 0; mi < 4; ++mi)
      #pragma unroll
      for (int ni = 0; ni < 4; ++ni)
        acc[mi][ni] = __builtin_amdgcn_mfma_f32_16x16x32_bf16(fa[mi], fb[ni], acc[mi][ni], 0, 0, 0);
  }
  const int rg = (lane >> 4) * 4;
  #pragma unroll
  for (int ni = 0; ni < 4; ++ni) {
    int col = col0 + wc*64 + ni*16 + m16;
    float bb = bg[col];
    int gate = col >> 9, hcol = col & 511;
    int cg = hcol >> 3, n = gate * 8 + (hcol & 7);
    #pragma unroll
    for (int mi = 0; mi < 4; ++mi)
      #pragma unroll
      for (int r = 0; r < 4; ++r) {
        int row = row0 + wr*64 + mi*16 + rg + r;
        Zx2[((size_t)cg * 2048 + row) * 32 + n] = acc[mi][ni][r] + bb;
      }
  }
}

// ---------------------------------------------------------------- gemm_x (standalone, chunk 0)
__global__ __launch_bounds__(256) void gemm_x_kernel(
    const float* __restrict__ X, const unsigned short* __restrict__ WxT,
    const float* __restrict__ bg, float* __restrict__ Zx2)
{
  __shared__ SMem sm;
  gemm_x_tile(sm, X, WxT, bg, Zx2, blockIdx.x * 128, blockIdx.y * 128, threadIdx.x);
}

// ---------------------------------------------------------------- fused: rec (blk 0..63) + next-chunk gemm_x (blk 64..255)
__global__ __launch_bounds__(256, 1) void lstm_fused_kernel(
    const unsigned short* __restrict__ WhB,  // [64][32][512] bf16 swizzled
    const float* __restrict__ Zxcur,         // [64][2048][32] this chunk
    unsigned short* __restrict__ hsx,        // [513][...] bf16, chunked layout
    float* __restrict__ cbuf,                // [64][512] fp32
    int step0,
    unsigned int* __restrict__ flags,        // [64*kFP], flag at cg*kFP
    float* __restrict__ dout,
    const float* __restrict__ Xnext,         // next chunk x (null on last)
    const unsigned short* __restrict__ WxT,
    const float* __restrict__ bg,
    float* __restrict__ Zxnext)              // next chunk Zx buffer
{
  __shared__ SMem sm;
  const int tid = threadIdx.x;

  if (blockIdx.x >= 64) {
    // ---------------- gemm role: compute Zx for chunk c+1 ----------------
    if (Xnext == nullptr) return;
    for (int tile = (int)blockIdx.x - 64; tile < 256; tile += 192) {
      gemm_x_tile(sm, Xnext, WxT, bg, Zxnext, (tile >> 4) * 128, (tile & 15) * 128, tid);
      __syncthreads();
    }
    return;
  }

  // ---------------- rec role ----------------
  const int cg = blockIdx.x;
  const int j0 = cg * 8;
  const int w   = tid >> 6;           // wave 0..3 -> batch rows w*16..+16
  const int l   = tid & 63;
  const int q   = l & 15;             // n-col within frag
  const int lg  = l >> 4;             // k-group
  const int jj  = q & 7;
  const int i0  = (q < 8) ? 0 : 2;    // acc rows this lane finishes

  // one-time: W slice -> LDS (linear copy; swizzle pre-applied by prep)
  {
    const uint4* wsrc = (const uint4*)(WhB + (size_t)cg * 32 * 512);
    uint4* wdst = (uint4*)sm.WT;
    #pragma unroll
    for (int i = 0; i < 8; ++i) wdst[i * 256 + tid] = wsrc[i * 256 + tid];
  }
  const size_t cidx = (size_t)(w * 16 + lg * 4 + i0) * 512 + j0 + jj;
  float c0r = cbuf[cidx];
  float c1r = cbuf[cidx + 512];
  __syncthreads();

  // Zx for t=0
  float zc0[4], zc1[4];
  {
    const float* zb = Zxcur + ((size_t)cg * 2048 + (w * 16 + lg * 4)) * 32 + q;
    #pragma unroll
    for (int i = 0; i < 4; ++i) { zc0[i] = zb[i * 32]; zc1[i] = zb[i * 32 + 16]; }
  }

  for (int t = 0; t < kT; ++t) {
    const int st = step0 + t;

    // wait for hsx[st] (skip t=0: previous dispatch completed it).
    // Wave 0 polls: lane l watches flags[l*kFP] (64 distinct lines -> no
    // hot-line TCC serialization). Others wait at barrier.
    if (t > 0) {
      if (tid < 64) {
        for (;;) {
          int fv = (int)__hip_atomic_load(&flags[l * kFP], __ATOMIC_RELAXED,
                                          __HIP_MEMORY_SCOPE_AGENT);
          if (__all(fv >= st)) break;
        }
      }
      __syncthreads();
    }

    // A-frags from chunked layout: A[s] = row w*16+q, cols 8*(4s+lg)..+7
    const unsigned short* hrow =
        hsx + (size_t)st * kHS + (size_t)lg * 512 + w * 128 + q * 8;
    bf16x8 A[16];
    #pragma unroll
    for (int s = 0; s < 16; ++s) A[s] = *(const bf16x8*)(hrow + 2048 * s);

    // Zx prefetch for t+1 issued BEFORE MFMA: completes under compute, so the
    // vmcnt(0) drain below only pays the h-store round trip.
    float zn0[4], zn1[4];
    if (t + 1 < kT) {
      const float* zb = Zxcur +
          ((size_t)cg * 2048 + ((t + 1) * 64 + w * 16 + lg * 4)) * 32 + q;
      #pragma unroll
      for (int i = 0; i < 4; ++i) { zn0[i] = zb[i * 32]; zn1[i] = zb[i * 32 + 16]; }
    }

    // MFMA: 16 ksteps x 2 n-frags
    f32x4 acc0 = {}, acc1 = {};
    #pragma unroll
    for (int s = 0; s < 16; ++s) {
      const int kb = 4 * s + lg;
      bf16x8 b0 = *(const bf16x8*)&sm.WT[(size_t)q * 512 + ((kb ^ jj) << 3)];
      bf16x8 b1 = *(const bf16x8*)&sm.WT[(size_t)(16 + q) * 512 + ((kb ^ jj) << 3)];
      acc0 = __builtin_amdgcn_mfma_f32_16x16x32_bf16(A[s], b0, acc0, 0, 0, 0);
      acc1 = __builtin_amdgcn_mfma_f32_16x16x32_bf16(A[s], b1, acc1, 0, 0, 0);
    }

    // z = acc + Zx (own cols), then exchange with lane^8 to gather 4 gates
    float t0[4], t1[4], ot0[4], ot1[4];
    #pragma unroll
    for (int i = 0; i < 4; ++i) { t0[i] = acc0[i] + zc0[i]; t1[i] = acc1[i] + zc1[i]; }
    #pragma unroll
    for (int i = 0; i < 4; ++i) {
      ot0[i] = __shfl_xor(t0[i], 8, 64);
      ot1[i] = __shfl_xor(t1[i], 8, 64);
    }
    float hh[2];
    #pragma unroll
    for (int u = 0; u < 2; ++u) {
      const int i = i0 + u;
      float zf = (q < 8) ? t0[i] : ot0[i];
      float zc = (q < 8) ? ot0[i] : t0[i];
      float zi = (q < 8) ? t1[i] : ot1[i];
      float zo = (q < 8) ? ot1[i] : t1[i];
      float fg = sigm(zf), ig = sigm(zi), og = sigm(zo);
      float Ct = tanh_f(zc);
      float& cr = u ? c1r : c0r;
      cr = fg * cr + ig * Ct;
      hh[u] = og * tanh_f(cr);
    }

    // store h: wave's 16x8 tile is ONE contiguous 256 B block (R7)
    {
      unsigned short hb0 = f2bf(hh[0]), hb1 = f2bf(hh[1]);
      unsigned o0 = (unsigned)(unsigned short)__shfl_xor((int)hb0, 1, 64);
      unsigned o1 = (unsigned)(unsigned short)__shfl_xor((int)hb1, 1, 64);
      if ((q & 1) == 0) {
        const size_t base = (size_t)(st + 1) * kHS + (size_t)cg * 512 +
                            w * 128 + (lg * 4 + i0) * 8 + jj;
        __hip_atomic_store((unsigned*)&hsx[base], ((unsigned)hb0) | (o0 << 16),
                           __ATOMIC_RELAXED, __HIP_MEMORY_SCOPE_AGENT);
        __hip_atomic_store((unsigned*)&hsx[base + 8], ((unsigned)hb1) | (o1 << 16),
                           __ATOMIC_RELAXED, __HIP_MEMORY_SCOPE_AGENT);
      }
      if (st == kL - 1) {
        dout[kOutSz + cidx] = hh[0];
        dout[kOutSz + cidx + 512] = hh[1];
        dout[kOutSz + (size_t)kN * kDH + cidx] = c0r;
        dout[kOutSz + (size_t)kN * kDH + cidx + 512] = c1r;
      }
    }

    // drain h stores, then publish flag (own 64B line)
    asm volatile("s_waitcnt vmcnt(0)" ::: "memory");
    __syncthreads();
    if (tid == 0)
      __hip_atomic_store(&flags[cg * kFP], (unsigned)(st + 1), __ATOMIC_RELAXED,
                         __HIP_MEMORY_SCOPE_AGENT);

    if (t + 1 < kT) {
      #pragma unroll
      for (int i = 0; i < 4; ++i) { zc0[i] = zn0[i]; zc1[i] = zn1[i]; }
    }
  }

  cbuf[cidx] = c0r;
  cbuf[cidx + 512] = c1r;
}

// ---------------------------------------------------------------- gemm_out
__global__ __launch_bounds__(256) void gemm_out_kernel(
    const unsigned short* __restrict__ Hs,   // hsx + 32768: h_1.. in chunked layout
    const unsigned short* __restrict__ WoT,  // [512][512] bf16 (B^T)
    const float* __restrict__ bout,
    float* __restrict__ out)                 // [32768][512] fp32
{
  __shared__ unsigned short Ash[128][40];
  __shared__ unsigned short Bsh[128][40];
  const int row0 = blockIdx.x * 128, col0 = blockIdx.y * 128;
  const int tid = threadIdx.x;
  const int lane = tid & 63, wave = tid >> 6;
  const int wr = wave >> 1, wc = wave & 1;
  const int m16 = lane & 15, kg = (lane >> 4) * 8;

  f32x4 acc[4][4] = {};

  for (int k0 = 0; k0 < 512; k0 += 32) {
    __syncthreads();
    #pragma unroll
    for (int i = 0; i < 2; ++i) {
      int idx = i * 256 + tid;
      int r = idx >> 2, kq = idx & 3;
      int grow = row0 + r;               // h row: t*64 + n  (t = step-1)
      size_t src = (size_t)(grow >> 6) * kHS + (size_t)((k0 >> 3) + kq) * 512 +
                   ((grow >> 4) & 3) * 128 + (grow & 15) * 8;
      *(uint4*)&Ash[r][kq * 8] = *(const uint4*)&Hs[src];
    }
    #pragma unroll
    for (int i = 0; i < 2; ++i) {
      int idx = i * 256 + tid;
      int c = idx >> 2, kq = idx & 3;
      *(uint4*)&Bsh[c][kq * 8] =
          *(const uint4*)&WoT[(size_t)(col0 + c) * 512 + k0 + kq * 8];
    }
    __syncthreads();
    bf16x8 fa[4], fb[4];
    #pragma unroll
    for (int mi = 0; mi < 4; ++mi) fa[mi] = *(const bf16x8*)&Ash[wr*64 + mi*16 + m16][kg];
    #pragma unroll
    for (int ni = 0; ni < 4; ++ni) fb[ni] = *(const bf16x8*)&Bsh[wc*64 + ni*16 + m16][kg];
    #pragma unroll
    for (int mi = 0; mi < 4; ++mi)
      #pragma unroll
      for (int ni = 0; ni < 4; ++ni)
        acc[mi][ni] = __builtin_amdgcn_mfma_f32_16x16x32_bf16(fa[mi], fb[ni], acc[mi][ni], 0, 0, 0);
  }
  const int rg = (lane >> 4) * 4;
  #pragma unroll
  for (int ni = 0; ni < 4; ++ni) {
    int col = col0 + wc*64 + ni*16 + m16;
    float bb = bout[col];
    #pragma unroll
    for (int mi = 0; mi < 4; ++mi)
      #pragma unroll
      for (int r = 0; r < 4; ++r)
        out[(size_t)(row0 + wr*64 + mi*16 + rg + r) * 512 + col] = acc[mi][ni][r] + bb;
  }
}

// ---------------------------------------------------------------- launch
extern "C" void kernel_launch(void* const* d_in, const int* in_sizes, int n_in,
                              void* d_out, int out_size, void* d_ws, size_t ws_size,
                              hipStream_t stream) {
  (void)in_sizes; (void)n_in; (void)out_size; (void)ws_size;
  const float* x    = (const float*)d_in[0];
  const float* h0   = (const float*)d_in[1];
  const float* c0   = (const float*)d_in[2];
  const float* Wf   = (const float*)d_in[3];
  const float* bf_  = (const float*)d_in[4];
  const float* Wc   = (const float*)d_in[5];
  const float* bc_  = (const float*)d_in[6];
  const float* Wi_  = (const float*)d_in[7];
  const float* bi_  = (const float*)d_in[8];
  const float* Wo   = (const float*)d_in[9];
  const float* bo_  = (const float*)d_in[10];
  const float* Wout = (const float*)d_in[11];
  const float* bout = (const float*)d_in[12];
  float* out = (float*)d_out;

  char* ws = (char*)d_ws;
  size_t off = 0;
  auto alloc = [&](size_t bytes) -> void* {
    void* p = ws + off;
    off += (bytes + 255) & ~(size_t)255;
    return p;
  };
  float*          ZxA = (float*)alloc((size_t)kT * kN * kG * 4);                 // 16 MB
  float*          ZxB = (float*)alloc((size_t)kT * kN * kG * 4);                 // 16 MB
  unsigned short* hsx = (unsigned short*)alloc((size_t)(kL + 1) * kN * kDH * 2); // 33.6 MB
  unsigned short* WxT = (unsigned short*)alloc((size_t)kG * 512 * 2);            // 2 MB
  unsigned short* WoT = (unsigned short*)alloc((size_t)512 * 512 * 2);           // 0.5 MB
  unsigned short* WhB = (unsigned short*)alloc((size_t)64 * 32 * 512 * 2);       // 2 MB
  float*          bg  = (float*)alloc((size_t)kG * 4);
  float*          cbf = (float*)alloc((size_t)kN * kDH * 4);
  unsigned int*   flg = (unsigned int*)alloc((size_t)64 * kFP * 4);              // 4 KB

  prep_kernel<<<1024, 256, 0, stream>>>(Wf, Wc, Wi_, Wo, bf_, bc_, bi_, bo_,
                                        Wout, h0, c0, WxT, WoT, WhB, bg, hsx, cbf, flg);
  // chunk 0's Zx
  gemm_x_kernel<<<dim3(16, 16), 256, 0, stream>>>(x, WxT, bg, ZxA);
  for (int c = 0; c < kChunks; ++c) {
    float* Zxcur = (c & 1) ? ZxB : ZxA;
    float* Zxnxt = (c & 1) ? ZxA : ZxB;
    const float* xnext = (c + 1 < kChunks)
        ? x + (size_t)(c + 1) * kT * kN * kDIN : nullptr;
    lstm_fused_kernel<<<256, 256, 0, stream>>>(
        WhB, Zxcur, hsx, cbf, c * kT, flg, out, xnext, WxT, bg, Zxnxt);
  }
  gemm_out_kernel<<<dim3(256, 4), 256, 0, stream>>>(
      hsx + (size_t)kN * kDH, WoT, bout, out);
}